// Round 15
// baseline (565.082 us; speedup 1.0000x reference)
//
#include <hip/hip_runtime.h>
#include <math.h>
#include <stdint.h>

#define N_ENT   100000
#define DIM     200
#define HD      100       // DIM/2
#define N_RELC  200
#define KP      608       // padded K: 3*200 -> 19*32
#define BM      128
#define BNN     256       // padded N (200 -> 256)
#define NT      19        // K steps of 32
#define MPAD    100096    // 782 * 128
#define SCAN_B  2048
#define SCAN_NB 49        // ceil(N_ENT / SCAN_B)

// fused prep kernel block ranges
#define CE_B    25000     // conv_ent: 4 rows/block
#define CR_B    100       // conv_rel elementwise
#define PB_B    608       // prep_bt
#define DEG_B   1024      // deg grid-stride

typedef uint32_t u32;
typedef __attribute__((ext_vector_type(8))) short bf16x8;
typedef __attribute__((ext_vector_type(4))) float f32x4;

__device__ __forceinline__ float invsqrt_pos(float x) {
    return x > 0.f ? (1.f / sqrtf(x)) : 0.f;
}

__device__ __forceinline__ u32 pack_bf16x2(float a, float b) {
    u32 ua = __float_as_uint(a), ub = __float_as_uint(b);
    ua = (ua + 0x7FFFu + ((ua >> 16) & 1u)) >> 16;
    ub = (ub + 0x7FFFu + ((ub >> 16) & 1u)) >> 16;
    return ua | (ub << 16);
}

__device__ __forceinline__ float bf_lo(u32 u) { return __uint_as_float(u << 16); }
__device__ __forceinline__ float bf_hi(u32 u) { return __uint_as_float(u & 0xFFFF0000u); }

// global -> LDS direct copy, 16B per lane (dest must be linear in lane id)
__device__ __forceinline__ void lds_cp16(void* lds, const void* g) {
    auto gp = (const __attribute__((address_space(1))) u32*)(uintptr_t)g;
    auto lp = (__attribute__((address_space(3))) u32*)(u32)(uintptr_t)lds;
    __builtin_amdgcn_global_load_lds(gp, lp, 16, 0, 0);
}

// Fused prep: conv_ent | conv_rel | prep_bt | deg, role by blockIdx.
// conv_ent: SPLIT bf16 ent16 row [re(100)|im(100)] + f32 self-loop rotation
//           into Abuf cols [400..600) + zero pad [600..608).
// conv_rel: elementwise f32 -> bf16 (split layout preserved).
__global__ __launch_bounds__(256) void prep_kernel(
        const float* __restrict__ ent, const float* __restrict__ rel,
        const float* __restrict__ loop_rel,
        const float* __restrict__ w_in, const float* __restrict__ w_out,
        const float* __restrict__ w_loop,
        const int* __restrict__ src, const int* __restrict__ dst,
        ushort* __restrict__ ent16, ushort* __restrict__ rel16,
        ushort* __restrict__ BT, ushort* __restrict__ Abuf,
        int* __restrict__ deg_in, int* __restrict__ deg_out, int n_edge) {
    const int b = blockIdx.x;
    const int tid = threadIdx.x;
    if (b < CE_B) {
        int row  = (b * 256 + tid) >> 6;
        int lane = tid & 63;
        if (row >= N_ENT) return;
        u32* Arow = (u32*)(Abuf + (size_t)row * KP);
        if (lane < 50) {
            const float* h = ent + (size_t)row * DIM;
            float2 re = *(const float2*)(h + 2 * lane);
            float2 im = *(const float2*)(h + HD + 2 * lane);
            u32* e32 = (u32*)(ent16 + (size_t)row * DIM);
            e32[lane]      = pack_bf16x2(re.x, re.y);
            e32[50 + lane] = pack_bf16x2(im.x, im.y);
            float2 lre = *(const float2*)(loop_rel + 2 * lane);
            float2 lim = *(const float2*)(loop_rel + HD + 2 * lane);
            float rx = re.x * lre.x - im.x * lim.x;
            float ry = re.y * lre.y - im.y * lim.y;
            float ix = re.x * lim.x + im.x * lre.x;
            float iy = re.y * lim.y + im.y * lre.y;
            Arow[200 + lane] = pack_bf16x2(rx, ry);
            Arow[250 + lane] = pack_bf16x2(ix, iy);
        } else if (lane < 54) {
            Arow[300 + (lane - 50)] = 0u;
        }
    } else if (b < CE_B + CR_B) {
        int i = (b - CE_B) * 256 + tid;
        const int n4 = 2 * N_RELC * DIM / 4;   // 20000
        if (i < n4) {
            float4 v = ((const float4*)rel)[i];
            uint2 o;
            o.x = pack_bf16x2(v.x, v.y);
            o.y = pack_bf16x2(v.z, v.w);
            ((uint2*)rel16)[i] = o;
        }
    } else if (b < CE_B + CR_B + PB_B) {
        int i = (b - CE_B - CR_B) * 256 + tid;
        if (i >= 256 * KP) return;
        int c = i / KP, k = i % KP;
        float v = 0.f;
        if (c < DIM) {
            if (k < 200)      v = w_in[k * DIM + c];
            else if (k < 400) v = w_out[(k - 200) * DIM + c];
            else if (k < 600) v = w_loop[(k - 400) * DIM + c];
        }
        u32 u = __float_as_uint(v);
        u = (u + 0x7FFFu + ((u >> 16) & 1u)) >> 16;
        BT[i] = (ushort)u;
    } else {
        int i = (b - CE_B - CR_B - PB_B) * 256 + tid;
        int stride = DEG_B * 256;
        for (; i < n_edge; i += stride) {
            atomicAdd(&deg_in[dst[i]], 1);
            atomicAdd(&deg_out[src[i]], 1);
        }
    }
}

// Hierarchical scan, pass A: per-block partial sums (8 elems/thread).
__global__ __launch_bounds__(256) void scan_part_kernel(
        const int* __restrict__ deg_in, const int* __restrict__ deg_out,
        int* __restrict__ partials) {
    int dir = blockIdx.x >= SCAN_NB;
    int blk = blockIdx.x - dir * SCAN_NB;
    const int* deg = dir ? deg_out : deg_in;
    int t = threadIdx.x;
    int base = blk * SCAN_B + t * 8;
    int s = 0;
#pragma unroll
    for (int u = 0; u < 8; ++u) {
        int i = base + u;
        if (i < N_ENT) s += deg[i];
    }
    __shared__ int red[256];
    red[t] = s;
    __syncthreads();
    for (int d = 128; d > 0; d >>= 1) {
        if (t < d) red[t] += red[t + d];
        __syncthreads();
    }
    if (t == 0) partials[dir * SCAN_NB + blk] = red[0];
}

// Pass B (folded): per-block scan + base from raw partials; write off/cur/inv.
__global__ __launch_bounds__(256) void scan_apply_kernel(
        const int* __restrict__ deg_in, const int* __restrict__ deg_out,
        const int* __restrict__ partials,
        int* __restrict__ off_in, int* __restrict__ off_out,
        int* __restrict__ cur_in, int* __restrict__ cur_out,
        float* __restrict__ inv_in, float* __restrict__ inv_out) {
    int dir = blockIdx.x >= SCAN_NB;
    int blk = blockIdx.x - dir * SCAN_NB;
    const int* deg = dir ? deg_out : deg_in;
    int* off   = dir ? off_out : off_in;
    int* cur   = dir ? cur_out : cur_in;
    float* inv = dir ? inv_out : inv_in;
    int t = threadIdx.x;
    int base = blk * SCAN_B + t * 8;
    int v[8];
    int s = 0;
#pragma unroll
    for (int u = 0; u < 8; ++u) {
        int i = base + u;
        v[u] = (i < N_ENT) ? deg[i] : 0;
        s += v[u];
    }
    __shared__ int red[256];
    red[t] = s;
    __syncthreads();
    for (int d = 1; d < 256; d <<= 1) {
        int x = (t >= d) ? red[t - d] : 0;
        __syncthreads();
        red[t] += x;
        __syncthreads();
    }
    int base_off = 0;
    for (int bq = 0; bq < blk; ++bq) base_off += partials[dir * SCAN_NB + bq];
    int run = base_off + red[t] - s;
#pragma unroll
    for (int u = 0; u < 8; ++u) {
        int i = base + u;
        if (i < N_ENT) {
            off[i] = run;
            cur[i] = run;
            inv[i] = invsqrt_pos((float)v[u]);
            run += v[u];
            if (i == N_ENT - 1) off[N_ENT] = run;
        }
    }
}

// CSR fill, 4-way batched phases (loads / atomics / stores).
// Grid 2048 blocks = 8 blocks/CU for TLP on top of per-thread batching.
__global__ __launch_bounds__(256) void fill_kernel(
        const int* __restrict__ src, const int* __restrict__ dst,
        const int* __restrict__ etype,
        int* cur_in, int* cur_out,
        u32* __restrict__ csr_in, u32* __restrict__ csr_out, int n) {
    int tid  = blockIdx.x * blockDim.x + threadIdx.x;
    int nthr = gridDim.x * blockDim.x;
    for (int base = tid; base < n; base += 4 * nthr) {
        int i0 = base;
        int i1 = base + nthr;
        int i2 = base + 2 * nthr;
        int i3 = base + 3 * nthr;
        bool k1 = i1 < n, k2 = i2 < n, k3 = i3 < n;
        int s0 = src[i0], d0 = dst[i0], e0 = etype[i0];
        int s1 = 0, d1 = 0, e1 = 0, s2 = 0, d2 = 0, e2 = 0, s3 = 0, d3 = 0, e3 = 0;
        if (k1) { s1 = src[i1]; d1 = dst[i1]; e1 = etype[i1]; }
        if (k2) { s2 = src[i2]; d2 = dst[i2]; e2 = etype[i2]; }
        if (k3) { s3 = src[i3]; d3 = dst[i3]; e3 = etype[i3]; }
        int pi0 = atomicAdd(&cur_in[d0], 1);
        int po0 = atomicAdd(&cur_out[s0], 1);
        int pi1 = 0, po1 = 0, pi2 = 0, po2 = 0, pi3 = 0, po3 = 0;
        if (k1) { pi1 = atomicAdd(&cur_in[d1], 1); po1 = atomicAdd(&cur_out[s1], 1); }
        if (k2) { pi2 = atomicAdd(&cur_in[d2], 1); po2 = atomicAdd(&cur_out[s2], 1); }
        if (k3) { pi3 = atomicAdd(&cur_in[d3], 1); po3 = atomicAdd(&cur_out[s3], 1); }
        csr_in[pi0]  = ((u32)s0 << 8) | (u32)e0;
        csr_out[po0] = ((u32)d0 << 8) | (u32)e0;
        if (k1) { csr_in[pi1]  = ((u32)s1 << 8) | (u32)e1;
                  csr_out[po1] = ((u32)d1 << 8) | (u32)e1; }
        if (k2) { csr_in[pi2]  = ((u32)s2 << 8) | (u32)e2;
                  csr_out[po2] = ((u32)d2 << 8) | (u32)e2; }
        if (k3) { csr_in[pi3]  = ((u32)s3 << 8) | (u32)e3;
                  csr_out[po3] = ((u32)d3 << 8) | (u32)e3; }
    }
}

// One wave per node; 4 independent accumulator chains; bf16 split tables
// (r13 known-good structure, 164us).
__global__ __launch_bounds__(256) void gather_kernel(
        const ushort* __restrict__ ent16, const ushort* __restrict__ rel16,
        const u32* __restrict__ csr_in, const u32* __restrict__ csr_out,
        const int* __restrict__ off_in, const int* __restrict__ off_out,
        const float* __restrict__ inv_in, const float* __restrict__ inv_out,
        ushort* __restrict__ Abuf) {
    int node = (blockIdx.x * blockDim.x + threadIdx.x) >> 6;
    int lane = threadIdx.x & 63;
    if (node >= N_ENT) return;
    const bool act = lane < 50;
    u32* Arow = (u32*)(Abuf + (size_t)node * KP);

#pragma unroll
    for (int dir = 0; dir < 2; ++dir) {
        const u32* csr = dir ? csr_out : csr_in;
        const int* off = dir ? off_out : off_in;
        const float* inv = dir ? inv_out : inv_in;
        const int tofs = dir ? N_RELC : 0;
        float myinv = inv[node];
        float2 are = {0.f, 0.f}, aim = {0.f, 0.f};   // chain A
        float2 bre = {0.f, 0.f}, bim = {0.f, 0.f};   // chain B
        float2 cre = {0.f, 0.f}, cim = {0.f, 0.f};   // chain C
        float2 dre = {0.f, 0.f}, dim_ = {0.f, 0.f};  // chain D
        int i0 = off[node], i1 = off[node + 1];
        int i = i0;
        for (; i + 3 < i1; i += 4) {
            u32 pk0 = csr[i],     pk1 = csr[i + 1];
            u32 pk2 = csr[i + 2], pk3 = csr[i + 3];
            int s0 = (int)(pk0 >> 8), t0 = (int)(pk0 & 255u) + tofs;
            int s1 = (int)(pk1 >> 8), t1 = (int)(pk1 & 255u) + tofs;
            int s2 = (int)(pk2 >> 8), t2 = (int)(pk2 & 255u) + tofs;
            int s3 = (int)(pk3 >> 8), t3 = (int)(pk3 & 255u) + tofs;
            float n0 = myinv * inv[s0];
            float n1 = myinv * inv[s1];
            float n2 = myinv * inv[s2];
            float n3 = myinv * inv[s3];
            if (act) {
                const u32* h0 = (const u32*)(ent16 + (size_t)s0 * DIM);
                const u32* r0 = (const u32*)(rel16 + (size_t)t0 * DIM);
                const u32* h1 = (const u32*)(ent16 + (size_t)s1 * DIM);
                const u32* r1 = (const u32*)(rel16 + (size_t)t1 * DIM);
                const u32* h2 = (const u32*)(ent16 + (size_t)s2 * DIM);
                const u32* r2 = (const u32*)(rel16 + (size_t)t2 * DIM);
                const u32* h3 = (const u32*)(ent16 + (size_t)s3 * DIM);
                const u32* r3 = (const u32*)(rel16 + (size_t)t3 * DIM);
                u32 hre0 = h0[lane], him0 = h0[50 + lane];
                u32 rre0 = r0[lane], rim0 = r0[50 + lane];
                u32 hre1 = h1[lane], him1 = h1[50 + lane];
                u32 rre1 = r1[lane], rim1 = r1[50 + lane];
                u32 hre2 = h2[lane], him2 = h2[50 + lane];
                u32 rre2 = r2[lane], rim2 = r2[50 + lane];
                u32 hre3 = h3[lane], him3 = h3[50 + lane];
                u32 rre3 = r3[lane], rim3 = r3[50 + lane];
                {
                    float ha = bf_lo(hre0), hb = bf_hi(hre0);
                    float ia = bf_lo(him0), ib = bf_hi(him0);
                    float ra = bf_lo(rre0), rb = bf_hi(rre0);
                    float ja = bf_lo(rim0), jb = bf_hi(rim0);
                    are.x += (ha * ra - ia * ja) * n0;
                    are.y += (hb * rb - ib * jb) * n0;
                    aim.x += (ha * ja + ia * ra) * n0;
                    aim.y += (hb * jb + ib * rb) * n0;
                }
                {
                    float ha = bf_lo(hre1), hb = bf_hi(hre1);
                    float ia = bf_lo(him1), ib = bf_hi(him1);
                    float ra = bf_lo(rre1), rb = bf_hi(rre1);
                    float ja = bf_lo(rim1), jb = bf_hi(rim1);
                    bre.x += (ha * ra - ia * ja) * n1;
                    bre.y += (hb * rb - ib * jb) * n1;
                    bim.x += (ha * ja + ia * ra) * n1;
                    bim.y += (hb * jb + ib * rb) * n1;
                }
                {
                    float ha = bf_lo(hre2), hb = bf_hi(hre2);
                    float ia = bf_lo(him2), ib = bf_hi(him2);
                    float ra = bf_lo(rre2), rb = bf_hi(rre2);
                    float ja = bf_lo(rim2), jb = bf_hi(rim2);
                    cre.x += (ha * ra - ia * ja) * n2;
                    cre.y += (hb * rb - ib * jb) * n2;
                    cim.x += (ha * ja + ia * ra) * n2;
                    cim.y += (hb * jb + ib * rb) * n2;
                }
                {
                    float ha = bf_lo(hre3), hb = bf_hi(hre3);
                    float ia = bf_lo(him3), ib = bf_hi(him3);
                    float ra = bf_lo(rre3), rb = bf_hi(rre3);
                    float ja = bf_lo(rim3), jb = bf_hi(rim3);
                    dre.x += (ha * ra - ia * ja) * n3;
                    dre.y += (hb * rb - ib * jb) * n3;
                    dim_.x += (ha * ja + ia * ra) * n3;
                    dim_.y += (hb * jb + ib * rb) * n3;
                }
            }
        }
        for (; i < i1; ++i) {   // 0-3 remainder into chain A
            u32 pk = csr[i];
            int s = (int)(pk >> 8), t = (int)(pk & 255u) + tofs;
            float nrm = myinv * inv[s];
            if (act) {
                const u32* h32 = (const u32*)(ent16 + (size_t)s * DIM);
                const u32* r32 = (const u32*)(rel16 + (size_t)t * DIM);
                u32 hre = h32[lane], him = h32[50 + lane];
                u32 rre = r32[lane], rim = r32[50 + lane];
                float ha = bf_lo(hre), hb = bf_hi(hre);
                float ia = bf_lo(him), ib = bf_hi(him);
                float ra = bf_lo(rre), rb = bf_hi(rre);
                float ja = bf_lo(rim), jb = bf_hi(rim);
                are.x += (ha * ra - ia * ja) * nrm;
                are.y += (hb * rb - ib * jb) * nrm;
                aim.x += (ha * ja + ia * ra) * nrm;
                aim.y += (hb * jb + ib * rb) * nrm;
            }
        }
        if (act) {
            are.x += bre.x + cre.x + dre.x;
            are.y += bre.y + cre.y + dre.y;
            aim.x += bim.x + cim.x + dim_.x;
            aim.y += bim.y + cim.y + dim_.y;
            Arow[dir * 100 + lane]      = pack_bf16x2(are.x, are.y);
            Arow[dir * 100 + 50 + lane] = pack_bf16x2(aim.x, aim.y);
        }
    }
}

// C = A(MPADxKP) @ BT^T -> pre (f32)*1/3 + bias; fused BN column stats.
__global__ __launch_bounds__(512, 4) void gemm_kernel(
        const ushort* __restrict__ A, const ushort* __restrict__ BT,
        const float* __restrict__ bias, float* __restrict__ out,
        float* __restrict__ stats) {
    __shared__ ushort Asm[2][BM * 32];
    __shared__ ushort Bsm[2][BNN * 32];
    __shared__ float sredS[8][4][16];
    __shared__ float sredQ[8][4][16];
    const int tid = threadIdx.x;
    const int row0 = blockIdx.x * BM;
    const int l = tid & 63;
    const int w = tid >> 6;
    const int wm = w >> 2;
    const int wn = w & 3;

    f32x4 acc[4][4];
#pragma unroll
    for (int i = 0; i < 4; ++i)
#pragma unroll
        for (int j = 0; j < 4; ++j)
            acc[i][j] = (f32x4){0.f, 0.f, 0.f, 0.f};

    {
        int r = tid >> 2, s = tid & 3;
        lds_cp16(&Asm[0][tid * 8], A + (size_t)(row0 + r) * KP + s * 8);
#pragma unroll
        for (int j = 0; j < 2; ++j) {
            int c = tid + j * 512;
            int br = c >> 2, bs = c & 3;
            lds_cp16(&Bsm[0][c * 8], BT + (size_t)br * KP + bs * 8);
        }
    }

    int cur = 0;
    for (int ks = 0; ks < NT; ++ks) {
        __syncthreads();
        if (ks + 1 < NT) {
            const int k0 = (ks + 1) * 32;
            int r = tid >> 2, s = tid & 3;
            lds_cp16(&Asm[cur ^ 1][tid * 8], A + (size_t)(row0 + r) * KP + k0 + s * 8);
#pragma unroll
            for (int j = 0; j < 2; ++j) {
                int c = tid + j * 512;
                int br = c >> 2, bs = c & 3;
                lds_cp16(&Bsm[cur ^ 1][c * 8], BT + (size_t)br * KP + k0 + bs * 8);
            }
        }
        const int kq = (l >> 4) * 8;
        const int lr = l & 15;
        bf16x8 aF[4], bF[4];
#pragma unroll
        for (int mf = 0; mf < 4; ++mf)
            aF[mf] = *(const bf16x8*)&Asm[cur][(wm * 64 + mf * 16 + lr) * 32 + kq];
#pragma unroll
        for (int nf = 0; nf < 4; ++nf)
            bF[nf] = *(const bf16x8*)&Bsm[cur][(wn * 64 + nf * 16 + lr) * 32 + kq];
#pragma unroll
        for (int mf = 0; mf < 4; ++mf)
#pragma unroll
            for (int nf = 0; nf < 4; ++nf)
                acc[mf][nf] = __builtin_amdgcn_mfma_f32_16x16x32_bf16(
                        aF[mf], bF[nf], acc[mf][nf], 0, 0, 0);
        cur ^= 1;
    }

    const int lr = l & 15;
    const int rq = (l >> 4) * 4;
    float colS[4], colQ[4];
#pragma unroll
    for (int nf = 0; nf < 4; ++nf) { colS[nf] = 0.f; colQ[nf] = 0.f; }

#pragma unroll
    for (int nf = 0; nf < 4; ++nf) {
        int gcol = wn * 64 + nf * 16 + lr;
        bool cok = gcol < DIM;
        float b = cok ? bias[gcol] : 0.f;
#pragma unroll
        for (int mf = 0; mf < 4; ++mf) {
            int grow0 = row0 + wm * 64 + mf * 16 + rq;
#pragma unroll
            for (int r = 0; r < 4; ++r) {
                int grow = grow0 + r;
                if (grow < N_ENT && cok) {
                    float v = acc[mf][nf][r] * (1.f / 3.f) + b;
                    out[(size_t)grow * DIM + gcol] = v;
                    colS[nf] += v;
                    colQ[nf] += v * v;
                }
            }
        }
    }
#pragma unroll
    for (int nf = 0; nf < 4; ++nf) {
        colS[nf] += __shfl_down(colS[nf], 32);
        colS[nf] += __shfl_down(colS[nf], 16);
        colQ[nf] += __shfl_down(colQ[nf], 32);
        colQ[nf] += __shfl_down(colQ[nf], 16);
    }
    if (l < 16) {
#pragma unroll
        for (int nf = 0; nf < 4; ++nf) {
            sredS[w][nf][l] = colS[nf];
            sredQ[w][nf][l] = colQ[nf];
        }
    }
    __syncthreads();
    if (tid < DIM) {
        int wn_ = tid >> 6, nf_ = (tid >> 4) & 3, lr_ = tid & 15;
        float s = sredS[wn_][nf_][lr_] + sredS[wn_ + 4][nf_][lr_];
        float q = sredQ[wn_][nf_][lr_] + sredQ[wn_ + 4][nf_][lr_];
        atomicAdd(&stats[tid], s);
        atomicAdd(&stats[DIM + tid], q);
    }
}

// BN finalize + tanh; scale/shift derived from stats per block.
__global__ __launch_bounds__(256) void bn_tanh_kernel(
        float* __restrict__ out, const float* __restrict__ stats,
        const float* __restrict__ gamma, const float* __restrict__ beta) {
    __shared__ float ssc[DIM], ssh[DIM];
    int t = threadIdx.x;
    if (t < DIM) {
        float mean = stats[t] * (1.f / (float)N_ENT);
        float var  = stats[DIM + t] * (1.f / (float)N_ENT) - mean * mean;
        float scale = gamma[t] / sqrtf(var + 1e-5f);
        ssc[t] = scale;
        ssh[t] = beta[t] - mean * scale;
    }
    __syncthreads();
    size_t i = (size_t)blockIdx.x * blockDim.x + threadIdx.x;
    size_t stride = (size_t)gridDim.x * blockDim.x;
    const size_t n4 = (size_t)N_ENT * DIM / 4;
    float4* p = (float4*)out;
    for (; i < n4; i += stride) {
        int c = (int)((i * 4) % DIM);
        float4 v = p[i];
        v.x = tanhf(v.x * ssc[c]     + ssh[c]);
        v.y = tanhf(v.y * ssc[c + 1] + ssh[c + 1]);
        v.z = tanhf(v.z * ssc[c + 2] + ssh[c + 2]);
        v.w = tanhf(v.w * ssc[c + 3] + ssh[c + 3]);
        p[i] = v;
    }
}

extern "C" void kernel_launch(void* const* d_in, const int* in_sizes, int n_in,
                              void* d_out, int out_size, void* d_ws, size_t ws_size,
                              hipStream_t stream) {
    const float* ent      = (const float*)d_in[0];
    const float* rel      = (const float*)d_in[1];
    const float* loop_rel = (const float*)d_in[2];
    const float* w_in     = (const float*)d_in[3];
    const float* w_out    = (const float*)d_in[4];
    const float* w_loop   = (const float*)d_in[5];
    const float* bias     = (const float*)d_in[6];
    const float* gamma    = (const float*)d_in[7];
    const float* beta     = (const float*)d_in[8];
    const int*   eidx     = (const int*)d_in[9];
    const int*   etype    = (const int*)d_in[10];
    const int n_edge = in_sizes[10];
    const int* src = eidx;
    const int* dst = eidx + n_edge;

    // workspace layout
    ushort* Abuf   = (ushort*)d_ws;                        // MPAD*KP bf16 (121.7MB)
    ushort* BT     = Abuf + (size_t)MPAD * KP;             // 256*KP bf16
    int* deg_in    = (int*)(BT + 256 * KP);
    int* deg_out   = deg_in + N_ENT;
    int* off_in    = deg_out + N_ENT;
    int* off_out   = off_in + N_ENT + 1;
    int* cur_in    = off_out + N_ENT + 1;
    int* cur_out   = cur_in + N_ENT;
    float* inv_in  = (float*)(cur_out + N_ENT);
    float* inv_out = inv_in + N_ENT;
    int* partials  = (int*)(inv_out + N_ENT);              // 2*SCAN_NB
    u32* csr_in    = (u32*)(partials + 2 * SCAN_NB);       // n_edge
    u32* csr_out   = csr_in + n_edge;                      // n_edge
    float* stats   = (float*)(csr_out + n_edge);           // 2*DIM
    ushort* rel16  = (ushort*)(stats + 2 * DIM);           // 2*N_RELC*DIM bf16
    float* outp    = (float*)d_out;
    // bf16 entity table lives in d_out (dead until gemm writes it)
    ushort* ent16  = (ushort*)d_out;                       // 40MB

    hipMemsetAsync(deg_in, 0, (size_t)2 * N_ENT * sizeof(int), stream);
    hipMemsetAsync(stats, 0, (size_t)2 * DIM * sizeof(float), stream);

    prep_kernel<<<CE_B + CR_B + PB_B + DEG_B, 256, 0, stream>>>(
        ent, rel, loop_rel, w_in, w_out, w_loop, src, dst,
        ent16, rel16, BT, Abuf, deg_in, deg_out, n_edge);
    scan_part_kernel<<<2 * SCAN_NB, 256, 0, stream>>>(deg_in, deg_out, partials);
    scan_apply_kernel<<<2 * SCAN_NB, 256, 0, stream>>>(
        deg_in, deg_out, partials, off_in, off_out, cur_in, cur_out,
        inv_in, inv_out);
    fill_kernel<<<2048, 256, 0, stream>>>(src, dst, etype, cur_in, cur_out,
                                          csr_in, csr_out, n_edge);
    gather_kernel<<<25000, 256, 0, stream>>>(ent16, rel16, csr_in, csr_out,
                                             off_in, off_out, inv_in, inv_out, Abuf);
    gemm_kernel<<<MPAD / BM, 512, 0, stream>>>(Abuf, BT, bias, outp, stats);
    bn_tanh_kernel<<<2048, 256, 0, stream>>>(outp, stats, gamma, beta);
}

// Round 16
// 554.843 us; speedup vs baseline: 1.0185x; 1.0185x over previous
//
#include <hip/hip_runtime.h>
#include <math.h>
#include <stdint.h>

#define N_ENT   100000
#define DIM     200
#define HD      100       // DIM/2
#define N_RELC  200
#define KP      608       // padded K: 3*200 -> 19*32
#define BM      128
#define BNN     256       // padded N (200 -> 256)
#define NT      19        // K steps of 32
#define MPAD    100096    // 782 * 128
#define SCAN_B  2048
#define SCAN_NB 49        // ceil(N_ENT / SCAN_B)

// fused prep kernel block ranges
#define CE_B    25000     // conv_ent: 4 rows/block
#define CR_B    100       // conv_rel elementwise
#define PB_B    608       // prep_bt
#define DEG_B   1024      // deg grid-stride

typedef uint32_t u32;
typedef __attribute__((ext_vector_type(8))) short bf16x8;
typedef __attribute__((ext_vector_type(4))) float f32x4;

__device__ __forceinline__ float invsqrt_pos(float x) {
    return x > 0.f ? (1.f / sqrtf(x)) : 0.f;
}

__device__ __forceinline__ u32 pack_bf16x2(float a, float b) {
    u32 ua = __float_as_uint(a), ub = __float_as_uint(b);
    ua = (ua + 0x7FFFu + ((ua >> 16) & 1u)) >> 16;
    ub = (ub + 0x7FFFu + ((ub >> 16) & 1u)) >> 16;
    return ua | (ub << 16);
}

__device__ __forceinline__ float bf_lo(u32 u) { return __uint_as_float(u << 16); }
__device__ __forceinline__ float bf_hi(u32 u) { return __uint_as_float(u & 0xFFFF0000u); }

// global -> LDS direct copy, 16B per lane (dest must be linear in lane id)
__device__ __forceinline__ void lds_cp16(void* lds, const void* g) {
    auto gp = (const __attribute__((address_space(1))) u32*)(uintptr_t)g;
    auto lp = (__attribute__((address_space(3))) u32*)(u32)(uintptr_t)lds;
    __builtin_amdgcn_global_load_lds(gp, lp, 16, 0, 0);
}

// Fused prep: conv_ent | conv_rel | prep_bt | deg, role by blockIdx.
__global__ __launch_bounds__(256) void prep_kernel(
        const float* __restrict__ ent, const float* __restrict__ rel,
        const float* __restrict__ loop_rel,
        const float* __restrict__ w_in, const float* __restrict__ w_out,
        const float* __restrict__ w_loop,
        const int* __restrict__ src, const int* __restrict__ dst,
        ushort* __restrict__ ent16, ushort* __restrict__ rel16,
        ushort* __restrict__ BT, ushort* __restrict__ Abuf,
        int* __restrict__ deg_in, int* __restrict__ deg_out, int n_edge) {
    const int b = blockIdx.x;
    const int tid = threadIdx.x;
    if (b < CE_B) {
        int row  = (b * 256 + tid) >> 6;
        int lane = tid & 63;
        if (row >= N_ENT) return;
        u32* Arow = (u32*)(Abuf + (size_t)row * KP);
        if (lane < 50) {
            const float* h = ent + (size_t)row * DIM;
            float2 re = *(const float2*)(h + 2 * lane);
            float2 im = *(const float2*)(h + HD + 2 * lane);
            u32* e32 = (u32*)(ent16 + (size_t)row * DIM);
            e32[lane]      = pack_bf16x2(re.x, re.y);
            e32[50 + lane] = pack_bf16x2(im.x, im.y);
            float2 lre = *(const float2*)(loop_rel + 2 * lane);
            float2 lim = *(const float2*)(loop_rel + HD + 2 * lane);
            float rx = re.x * lre.x - im.x * lim.x;
            float ry = re.y * lre.y - im.y * lim.y;
            float ix = re.x * lim.x + im.x * lre.x;
            float iy = re.y * lim.y + im.y * lre.y;
            Arow[200 + lane] = pack_bf16x2(rx, ry);
            Arow[250 + lane] = pack_bf16x2(ix, iy);
        } else if (lane < 54) {
            Arow[300 + (lane - 50)] = 0u;
        }
    } else if (b < CE_B + CR_B) {
        int i = (b - CE_B) * 256 + tid;
        const int n4 = 2 * N_RELC * DIM / 4;   // 20000
        if (i < n4) {
            float4 v = ((const float4*)rel)[i];
            uint2 o;
            o.x = pack_bf16x2(v.x, v.y);
            o.y = pack_bf16x2(v.z, v.w);
            ((uint2*)rel16)[i] = o;
        }
    } else if (b < CE_B + CR_B + PB_B) {
        int i = (b - CE_B - CR_B) * 256 + tid;
        if (i >= 256 * KP) return;
        int c = i / KP, k = i % KP;
        float v = 0.f;
        if (c < DIM) {
            if (k < 200)      v = w_in[k * DIM + c];
            else if (k < 400) v = w_out[(k - 200) * DIM + c];
            else if (k < 600) v = w_loop[(k - 400) * DIM + c];
        }
        u32 u = __float_as_uint(v);
        u = (u + 0x7FFFu + ((u >> 16) & 1u)) >> 16;
        BT[i] = (ushort)u;
    } else {
        int i = (b - CE_B - CR_B - PB_B) * 256 + tid;
        int stride = DEG_B * 256;
        for (; i < n_edge; i += stride) {
            atomicAdd(&deg_in[dst[i]], 1);
            atomicAdd(&deg_out[src[i]], 1);
        }
    }
}

// Hierarchical scan, pass A: per-block partial sums (8 elems/thread).
__global__ __launch_bounds__(256) void scan_part_kernel(
        const int* __restrict__ deg_in, const int* __restrict__ deg_out,
        int* __restrict__ partials) {
    int dir = blockIdx.x >= SCAN_NB;
    int blk = blockIdx.x - dir * SCAN_NB;
    const int* deg = dir ? deg_out : deg_in;
    int t = threadIdx.x;
    int base = blk * SCAN_B + t * 8;
    int s = 0;
#pragma unroll
    for (int u = 0; u < 8; ++u) {
        int i = base + u;
        if (i < N_ENT) s += deg[i];
    }
    __shared__ int red[256];
    red[t] = s;
    __syncthreads();
    for (int d = 128; d > 0; d >>= 1) {
        if (t < d) red[t] += red[t + d];
        __syncthreads();
    }
    if (t == 0) partials[dir * SCAN_NB + blk] = red[0];
}

// Pass B (folded): per-block scan + base from raw partials; write off/cur/inv.
__global__ __launch_bounds__(256) void scan_apply_kernel(
        const int* __restrict__ deg_in, const int* __restrict__ deg_out,
        const int* __restrict__ partials,
        int* __restrict__ off_in, int* __restrict__ off_out,
        int* __restrict__ cur_in, int* __restrict__ cur_out,
        float* __restrict__ inv_in, float* __restrict__ inv_out) {
    int dir = blockIdx.x >= SCAN_NB;
    int blk = blockIdx.x - dir * SCAN_NB;
    const int* deg = dir ? deg_out : deg_in;
    int* off   = dir ? off_out : off_in;
    int* cur   = dir ? cur_out : cur_in;
    float* inv = dir ? inv_out : inv_in;
    int t = threadIdx.x;
    int base = blk * SCAN_B + t * 8;
    int v[8];
    int s = 0;
#pragma unroll
    for (int u = 0; u < 8; ++u) {
        int i = base + u;
        v[u] = (i < N_ENT) ? deg[i] : 0;
        s += v[u];
    }
    __shared__ int red[256];
    red[t] = s;
    __syncthreads();
    for (int d = 1; d < 256; d <<= 1) {
        int x = (t >= d) ? red[t - d] : 0;
        __syncthreads();
        red[t] += x;
        __syncthreads();
    }
    int base_off = 0;
    for (int bq = 0; bq < blk; ++bq) base_off += partials[dir * SCAN_NB + bq];
    int run = base_off + red[t] - s;
#pragma unroll
    for (int u = 0; u < 8; ++u) {
        int i = base + u;
        if (i < N_ENT) {
            off[i] = run;
            cur[i] = run;
            inv[i] = invsqrt_pos((float)v[u]);
            run += v[u];
            if (i == N_ENT - 1) off[N_ENT] = run;
        }
    }
}

// CSR fill, 4-way batched phases (loads / atomics / stores). 512 blocks
// (known-good r13 config: 8 edges/thread keeps 8 atomics in flight).
__global__ __launch_bounds__(256) void fill_kernel(
        const int* __restrict__ src, const int* __restrict__ dst,
        const int* __restrict__ etype,
        int* cur_in, int* cur_out,
        u32* __restrict__ csr_in, u32* __restrict__ csr_out, int n) {
    int tid  = blockIdx.x * blockDim.x + threadIdx.x;
    int nthr = gridDim.x * blockDim.x;
    for (int base = tid; base < n; base += 4 * nthr) {
        int i0 = base;
        int i1 = base + nthr;
        int i2 = base + 2 * nthr;
        int i3 = base + 3 * nthr;
        bool k1 = i1 < n, k2 = i2 < n, k3 = i3 < n;
        int s0 = src[i0], d0 = dst[i0], e0 = etype[i0];
        int s1 = 0, d1 = 0, e1 = 0, s2 = 0, d2 = 0, e2 = 0, s3 = 0, d3 = 0, e3 = 0;
        if (k1) { s1 = src[i1]; d1 = dst[i1]; e1 = etype[i1]; }
        if (k2) { s2 = src[i2]; d2 = dst[i2]; e2 = etype[i2]; }
        if (k3) { s3 = src[i3]; d3 = dst[i3]; e3 = etype[i3]; }
        int pi0 = atomicAdd(&cur_in[d0], 1);
        int po0 = atomicAdd(&cur_out[s0], 1);
        int pi1 = 0, po1 = 0, pi2 = 0, po2 = 0, pi3 = 0, po3 = 0;
        if (k1) { pi1 = atomicAdd(&cur_in[d1], 1); po1 = atomicAdd(&cur_out[s1], 1); }
        if (k2) { pi2 = atomicAdd(&cur_in[d2], 1); po2 = atomicAdd(&cur_out[s2], 1); }
        if (k3) { pi3 = atomicAdd(&cur_in[d3], 1); po3 = atomicAdd(&cur_out[s3], 1); }
        csr_in[pi0]  = ((u32)s0 << 8) | (u32)e0;
        csr_out[po0] = ((u32)d0 << 8) | (u32)e0;
        if (k1) { csr_in[pi1]  = ((u32)s1 << 8) | (u32)e1;
                  csr_out[po1] = ((u32)d1 << 8) | (u32)e1; }
        if (k2) { csr_in[pi2]  = ((u32)s2 << 8) | (u32)e2;
                  csr_out[po2] = ((u32)d2 << 8) | (u32)e2; }
        if (k3) { csr_in[pi3]  = ((u32)s3 << 8) | (u32)e3;
                  csr_out[po3] = ((u32)d3 << 8) | (u32)e3; }
    }
}

// One wave per node; 4 independent accumulator chains; bf16 split tables
// (r13 known-good structure, 164us).
__global__ __launch_bounds__(256) void gather_kernel(
        const ushort* __restrict__ ent16, const ushort* __restrict__ rel16,
        const u32* __restrict__ csr_in, const u32* __restrict__ csr_out,
        const int* __restrict__ off_in, const int* __restrict__ off_out,
        const float* __restrict__ inv_in, const float* __restrict__ inv_out,
        ushort* __restrict__ Abuf) {
    int node = (blockIdx.x * blockDim.x + threadIdx.x) >> 6;
    int lane = threadIdx.x & 63;
    if (node >= N_ENT) return;
    const bool act = lane < 50;
    u32* Arow = (u32*)(Abuf + (size_t)node * KP);

#pragma unroll
    for (int dir = 0; dir < 2; ++dir) {
        const u32* csr = dir ? csr_out : csr_in;
        const int* off = dir ? off_out : off_in;
        const float* inv = dir ? inv_out : inv_in;
        const int tofs = dir ? N_RELC : 0;
        float myinv = inv[node];
        float2 are = {0.f, 0.f}, aim = {0.f, 0.f};   // chain A
        float2 bre = {0.f, 0.f}, bim = {0.f, 0.f};   // chain B
        float2 cre = {0.f, 0.f}, cim = {0.f, 0.f};   // chain C
        float2 dre = {0.f, 0.f}, dim_ = {0.f, 0.f};  // chain D
        int i0 = off[node], i1 = off[node + 1];
        int i = i0;
        for (; i + 3 < i1; i += 4) {
            u32 pk0 = csr[i],     pk1 = csr[i + 1];
            u32 pk2 = csr[i + 2], pk3 = csr[i + 3];
            int s0 = (int)(pk0 >> 8), t0 = (int)(pk0 & 255u) + tofs;
            int s1 = (int)(pk1 >> 8), t1 = (int)(pk1 & 255u) + tofs;
            int s2 = (int)(pk2 >> 8), t2 = (int)(pk2 & 255u) + tofs;
            int s3 = (int)(pk3 >> 8), t3 = (int)(pk3 & 255u) + tofs;
            float n0 = myinv * inv[s0];
            float n1 = myinv * inv[s1];
            float n2 = myinv * inv[s2];
            float n3 = myinv * inv[s3];
            if (act) {
                const u32* h0 = (const u32*)(ent16 + (size_t)s0 * DIM);
                const u32* r0 = (const u32*)(rel16 + (size_t)t0 * DIM);
                const u32* h1 = (const u32*)(ent16 + (size_t)s1 * DIM);
                const u32* r1 = (const u32*)(rel16 + (size_t)t1 * DIM);
                const u32* h2 = (const u32*)(ent16 + (size_t)s2 * DIM);
                const u32* r2 = (const u32*)(rel16 + (size_t)t2 * DIM);
                const u32* h3 = (const u32*)(ent16 + (size_t)s3 * DIM);
                const u32* r3 = (const u32*)(rel16 + (size_t)t3 * DIM);
                u32 hre0 = h0[lane], him0 = h0[50 + lane];
                u32 rre0 = r0[lane], rim0 = r0[50 + lane];
                u32 hre1 = h1[lane], him1 = h1[50 + lane];
                u32 rre1 = r1[lane], rim1 = r1[50 + lane];
                u32 hre2 = h2[lane], him2 = h2[50 + lane];
                u32 rre2 = r2[lane], rim2 = r2[50 + lane];
                u32 hre3 = h3[lane], him3 = h3[50 + lane];
                u32 rre3 = r3[lane], rim3 = r3[50 + lane];
                {
                    float ha = bf_lo(hre0), hb = bf_hi(hre0);
                    float ia = bf_lo(him0), ib = bf_hi(him0);
                    float ra = bf_lo(rre0), rb = bf_hi(rre0);
                    float ja = bf_lo(rim0), jb = bf_hi(rim0);
                    are.x += (ha * ra - ia * ja) * n0;
                    are.y += (hb * rb - ib * jb) * n0;
                    aim.x += (ha * ja + ia * ra) * n0;
                    aim.y += (hb * jb + ib * rb) * n0;
                }
                {
                    float ha = bf_lo(hre1), hb = bf_hi(hre1);
                    float ia = bf_lo(him1), ib = bf_hi(him1);
                    float ra = bf_lo(rre1), rb = bf_hi(rre1);
                    float ja = bf_lo(rim1), jb = bf_hi(rim1);
                    bre.x += (ha * ra - ia * ja) * n1;
                    bre.y += (hb * rb - ib * jb) * n1;
                    bim.x += (ha * ja + ia * ra) * n1;
                    bim.y += (hb * jb + ib * rb) * n1;
                }
                {
                    float ha = bf_lo(hre2), hb = bf_hi(hre2);
                    float ia = bf_lo(him2), ib = bf_hi(him2);
                    float ra = bf_lo(rre2), rb = bf_hi(rre2);
                    float ja = bf_lo(rim2), jb = bf_hi(rim2);
                    cre.x += (ha * ra - ia * ja) * n2;
                    cre.y += (hb * rb - ib * jb) * n2;
                    cim.x += (ha * ja + ia * ra) * n2;
                    cim.y += (hb * jb + ib * rb) * n2;
                }
                {
                    float ha = bf_lo(hre3), hb = bf_hi(hre3);
                    float ia = bf_lo(him3), ib = bf_hi(him3);
                    float ra = bf_lo(rre3), rb = bf_hi(rre3);
                    float ja = bf_lo(rim3), jb = bf_hi(rim3);
                    dre.x += (ha * ra - ia * ja) * n3;
                    dre.y += (hb * rb - ib * jb) * n3;
                    dim_.x += (ha * ja + ia * ra) * n3;
                    dim_.y += (hb * jb + ib * rb) * n3;
                }
            }
        }
        for (; i < i1; ++i) {   // 0-3 remainder into chain A
            u32 pk = csr[i];
            int s = (int)(pk >> 8), t = (int)(pk & 255u) + tofs;
            float nrm = myinv * inv[s];
            if (act) {
                const u32* h32 = (const u32*)(ent16 + (size_t)s * DIM);
                const u32* r32 = (const u32*)(rel16 + (size_t)t * DIM);
                u32 hre = h32[lane], him = h32[50 + lane];
                u32 rre = r32[lane], rim = r32[50 + lane];
                float ha = bf_lo(hre), hb = bf_hi(hre);
                float ia = bf_lo(him), ib = bf_hi(him);
                float ra = bf_lo(rre), rb = bf_hi(rre);
                float ja = bf_lo(rim), jb = bf_hi(rim);
                are.x += (ha * ra - ia * ja) * nrm;
                are.y += (hb * rb - ib * jb) * nrm;
                aim.x += (ha * ja + ia * ra) * nrm;
                aim.y += (hb * jb + ib * rb) * nrm;
            }
        }
        if (act) {
            are.x += bre.x + cre.x + dre.x;
            are.y += bre.y + cre.y + dre.y;
            aim.x += bim.x + cim.x + dim_.x;
            aim.y += bim.y + cim.y + dim_.y;
            Arow[dir * 100 + lane]      = pack_bf16x2(are.x, are.y);
            Arow[dir * 100 + 50 + lane] = pack_bf16x2(aim.x, aim.y);
        }
    }
}

// C = A(MPADxKP) @ BT^T -> pre (f32)*1/3 + bias; fused BN column stats.
// B fragments loaded directly from global (BT is 311KB, L2-resident);
// only A double-buffered through LDS -> 20KB LDS, fewer barrier-gated bytes.
__global__ __launch_bounds__(512, 4) void gemm_kernel(
        const ushort* __restrict__ A, const ushort* __restrict__ BT,
        const float* __restrict__ bias, float* __restrict__ out,
        float* __restrict__ stats) {
    __shared__ ushort Asm[2][BM * 32];
    __shared__ float sredS[8][4][16];
    __shared__ float sredQ[8][4][16];
    const int tid = threadIdx.x;
    const int row0 = blockIdx.x * BM;
    const int l = tid & 63;
    const int w = tid >> 6;
    const int wm = w >> 2;
    const int wn = w & 3;

    f32x4 acc[4][4];
#pragma unroll
    for (int i = 0; i < 4; ++i)
#pragma unroll
        for (int j = 0; j < 4; ++j)
            acc[i][j] = (f32x4){0.f, 0.f, 0.f, 0.f};

    {   // stage A K-step 0 into buf 0 (256 lanes x 16B = 8KB; 512 threads: half)
        int r = tid >> 2, s = tid & 3;
        lds_cp16(&Asm[0][tid * 8], A + (size_t)(row0 + r) * KP + s * 8);
    }

    const int kq = (l >> 4) * 8;
    const int lr = l & 15;
    // per-lane B row pointers (4 nf fragments), advance by k each step
    const ushort* bptr[4];
#pragma unroll
    for (int nf = 0; nf < 4; ++nf)
        bptr[nf] = BT + (size_t)(wn * 64 + nf * 16 + lr) * KP + kq;

    int cur = 0;
    for (int ks = 0; ks < NT; ++ks) {
        // B fragments for this ks: straight from global/L2, not barrier-gated
        bf16x8 bF[4];
#pragma unroll
        for (int nf = 0; nf < 4; ++nf)
            bF[nf] = *(const bf16x8*)(bptr[nf] + ks * 32);
        __syncthreads();
        if (ks + 1 < NT) {
            const int k0 = (ks + 1) * 32;
            int r = tid >> 2, s = tid & 3;
            lds_cp16(&Asm[cur ^ 1][tid * 8], A + (size_t)(row0 + r) * KP + k0 + s * 8);
        }
        bf16x8 aF[4];
#pragma unroll
        for (int mf = 0; mf < 4; ++mf)
            aF[mf] = *(const bf16x8*)&Asm[cur][(wm * 64 + mf * 16 + lr) * 32 + kq];
#pragma unroll
        for (int mf = 0; mf < 4; ++mf)
#pragma unroll
            for (int nf = 0; nf < 4; ++nf)
                acc[mf][nf] = __builtin_amdgcn_mfma_f32_16x16x32_bf16(
                        aF[mf], bF[nf], acc[mf][nf], 0, 0, 0);
        cur ^= 1;
    }

    const int rq = (l >> 4) * 4;
    float colS[4], colQ[4];
#pragma unroll
    for (int nf = 0; nf < 4; ++nf) { colS[nf] = 0.f; colQ[nf] = 0.f; }

#pragma unroll
    for (int nf = 0; nf < 4; ++nf) {
        int gcol = wn * 64 + nf * 16 + lr;
        bool cok = gcol < DIM;
        float b = cok ? bias[gcol] : 0.f;
#pragma unroll
        for (int mf = 0; mf < 4; ++mf) {
            int grow0 = row0 + wm * 64 + mf * 16 + rq;
#pragma unroll
            for (int r = 0; r < 4; ++r) {
                int grow = grow0 + r;
                if (grow < N_ENT && cok) {
                    float v = acc[mf][nf][r] * (1.f / 3.f) + b;
                    out[(size_t)grow * DIM + gcol] = v;
                    colS[nf] += v;
                    colQ[nf] += v * v;
                }
            }
        }
    }
#pragma unroll
    for (int nf = 0; nf < 4; ++nf) {
        colS[nf] += __shfl_down(colS[nf], 32);
        colS[nf] += __shfl_down(colS[nf], 16);
        colQ[nf] += __shfl_down(colQ[nf], 32);
        colQ[nf] += __shfl_down(colQ[nf], 16);
    }
    if (l < 16) {
#pragma unroll
        for (int nf = 0; nf < 4; ++nf) {
            sredS[w][nf][l] = colS[nf];
            sredQ[w][nf][l] = colQ[nf];
        }
    }
    __syncthreads();
    if (tid < DIM) {
        int wn_ = tid >> 6, nf_ = (tid >> 4) & 3, lr_ = tid & 15;
        float s = sredS[wn_][nf_][lr_] + sredS[wn_ + 4][nf_][lr_];
        float q = sredQ[wn_][nf_][lr_] + sredQ[wn_ + 4][nf_][lr_];
        atomicAdd(&stats[tid], s);
        atomicAdd(&stats[DIM + tid], q);
    }
}

// BN finalize + tanh; scale/shift derived from stats per block.
__global__ __launch_bounds__(256) void bn_tanh_kernel(
        float* __restrict__ out, const float* __restrict__ stats,
        const float* __restrict__ gamma, const float* __restrict__ beta) {
    __shared__ float ssc[DIM], ssh[DIM];
    int t = threadIdx.x;
    if (t < DIM) {
        float mean = stats[t] * (1.f / (float)N_ENT);
        float var  = stats[DIM + t] * (1.f / (float)N_ENT) - mean * mean;
        float scale = gamma[t] / sqrtf(var + 1e-5f);
        ssc[t] = scale;
        ssh[t] = beta[t] - mean * scale;
    }
    __syncthreads();
    size_t i = (size_t)blockIdx.x * blockDim.x + threadIdx.x;
    size_t stride = (size_t)gridDim.x * blockDim.x;
    const size_t n4 = (size_t)N_ENT * DIM / 4;
    float4* p = (float4*)out;
    for (; i < n4; i += stride) {
        int c = (int)((i * 4) % DIM);
        float4 v = p[i];
        v.x = tanhf(v.x * ssc[c]     + ssh[c]);
        v.y = tanhf(v.y * ssc[c + 1] + ssh[c + 1]);
        v.z = tanhf(v.z * ssc[c + 2] + ssh[c + 2]);
        v.w = tanhf(v.w * ssc[c + 3] + ssh[c + 3]);
        p[i] = v;
    }
}

extern "C" void kernel_launch(void* const* d_in, const int* in_sizes, int n_in,
                              void* d_out, int out_size, void* d_ws, size_t ws_size,
                              hipStream_t stream) {
    const float* ent      = (const float*)d_in[0];
    const float* rel      = (const float*)d_in[1];
    const float* loop_rel = (const float*)d_in[2];
    const float* w_in     = (const float*)d_in[3];
    const float* w_out    = (const float*)d_in[4];
    const float* w_loop   = (const float*)d_in[5];
    const float* bias     = (const float*)d_in[6];
    const float* gamma    = (const float*)d_in[7];
    const float* beta     = (const float*)d_in[8];
    const int*   eidx     = (const int*)d_in[9];
    const int*   etype    = (const int*)d_in[10];
    const int n_edge = in_sizes[10];
    const int* src = eidx;
    const int* dst = eidx + n_edge;

    // workspace layout
    ushort* Abuf   = (ushort*)d_ws;                        // MPAD*KP bf16 (121.7MB)
    ushort* BT     = Abuf + (size_t)MPAD * KP;             // 256*KP bf16
    int* deg_in    = (int*)(BT + 256 * KP);
    int* deg_out   = deg_in + N_ENT;
    int* off_in    = deg_out + N_ENT;
    int* off_out   = off_in + N_ENT + 1;
    int* cur_in    = off_out + N_ENT + 1;
    int* cur_out   = cur_in + N_ENT;
    float* inv_in  = (float*)(cur_out + N_ENT);
    float* inv_out = inv_in + N_ENT;
    int* partials  = (int*)(inv_out + N_ENT);              // 2*SCAN_NB
    u32* csr_in    = (u32*)(partials + 2 * SCAN_NB);       // n_edge
    u32* csr_out   = csr_in + n_edge;                      // n_edge
    float* stats   = (float*)(csr_out + n_edge);           // 2*DIM
    ushort* rel16  = (ushort*)(stats + 2 * DIM);           // 2*N_RELC*DIM bf16
    float* outp    = (float*)d_out;
    // bf16 entity table lives in d_out (dead until gemm writes it)
    ushort* ent16  = (ushort*)d_out;                       // 40MB

    hipMemsetAsync(deg_in, 0, (size_t)2 * N_ENT * sizeof(int), stream);
    hipMemsetAsync(stats, 0, (size_t)2 * DIM * sizeof(float), stream);

    prep_kernel<<<CE_B + CR_B + PB_B + DEG_B, 256, 0, stream>>>(
        ent, rel, loop_rel, w_in, w_out, w_loop, src, dst,
        ent16, rel16, BT, Abuf, deg_in, deg_out, n_edge);
    scan_part_kernel<<<2 * SCAN_NB, 256, 0, stream>>>(deg_in, deg_out, partials);
    scan_apply_kernel<<<2 * SCAN_NB, 256, 0, stream>>>(
        deg_in, deg_out, partials, off_in, off_out, cur_in, cur_out,
        inv_in, inv_out);
    fill_kernel<<<512, 256, 0, stream>>>(src, dst, etype, cur_in, cur_out,
                                         csr_in, csr_out, n_edge);
    gather_kernel<<<25000, 256, 0, stream>>>(ent16, rel16, csr_in, csr_out,
                                             off_in, off_out, inv_in, inv_out, Abuf);
    gemm_kernel<<<MPAD / BM, 512, 0, stream>>>(Abuf, BT, bias, outp, stats);
    bn_tanh_kernel<<<2048, 256, 0, stream>>>(outp, stats, gamma, beta);
}

// Round 17
// 531.846 us; speedup vs baseline: 1.0625x; 1.0432x over previous
//
#include <hip/hip_runtime.h>
#include <math.h>
#include <stdint.h>

#define N_ENT   100000
#define DIM     200
#define HD      100       // DIM/2
#define N_RELC  200
#define KP      608       // padded K: 3*200 -> 19*32
#define BM      128
#define BNN     256       // padded N (200 -> 256)
#define NT      19        // K steps of 32
#define MPAD    100096    // 782 * 128
#define SCAN_B  2048
#define SCAN_NB 49        // ceil(N_ENT / SCAN_B)

// fused prep kernel block ranges
#define CE_B    25000     // conv_ent: 4 rows/block
#define CR_B    100       // conv_rel elementwise
#define PB_B    608       // prep_bt
#define DEG_B   1024      // deg grid-stride

typedef uint32_t u32;
typedef __attribute__((ext_vector_type(8))) short bf16x8;
typedef __attribute__((ext_vector_type(4))) float f32x4;

__device__ __forceinline__ float invsqrt_pos(float x) {
    return x > 0.f ? (1.f / sqrtf(x)) : 0.f;
}

__device__ __forceinline__ u32 pack_bf16x2(float a, float b) {
    u32 ua = __float_as_uint(a), ub = __float_as_uint(b);
    ua = (ua + 0x7FFFu + ((ua >> 16) & 1u)) >> 16;
    ub = (ub + 0x7FFFu + ((ub >> 16) & 1u)) >> 16;
    return ua | (ub << 16);
}

__device__ __forceinline__ float bf_lo(u32 u) { return __uint_as_float(u << 16); }
__device__ __forceinline__ float bf_hi(u32 u) { return __uint_as_float(u & 0xFFFF0000u); }

// global -> LDS direct copy, 16B per lane (dest must be linear in lane id)
__device__ __forceinline__ void lds_cp16(void* lds, const void* g) {
    auto gp = (const __attribute__((address_space(1))) u32*)(uintptr_t)g;
    auto lp = (__attribute__((address_space(3))) u32*)(u32)(uintptr_t)lds;
    __builtin_amdgcn_global_load_lds(gp, lp, 16, 0, 0);
}

// Fused prep: conv_ent | conv_rel | prep_bt | deg, role by blockIdx.
__global__ __launch_bounds__(256) void prep_kernel(
        const float* __restrict__ ent, const float* __restrict__ rel,
        const float* __restrict__ loop_rel,
        const float* __restrict__ w_in, const float* __restrict__ w_out,
        const float* __restrict__ w_loop,
        const int* __restrict__ src, const int* __restrict__ dst,
        ushort* __restrict__ ent16, ushort* __restrict__ rel16,
        ushort* __restrict__ BT, ushort* __restrict__ Abuf,
        int* __restrict__ deg_in, int* __restrict__ deg_out, int n_edge) {
    const int b = blockIdx.x;
    const int tid = threadIdx.x;
    if (b < CE_B) {
        int row  = (b * 256 + tid) >> 6;
        int lane = tid & 63;
        if (row >= N_ENT) return;
        u32* Arow = (u32*)(Abuf + (size_t)row * KP);
        if (lane < 50) {
            const float* h = ent + (size_t)row * DIM;
            float2 re = *(const float2*)(h + 2 * lane);
            float2 im = *(const float2*)(h + HD + 2 * lane);
            u32* e32 = (u32*)(ent16 + (size_t)row * DIM);
            e32[lane]      = pack_bf16x2(re.x, re.y);
            e32[50 + lane] = pack_bf16x2(im.x, im.y);
            float2 lre = *(const float2*)(loop_rel + 2 * lane);
            float2 lim = *(const float2*)(loop_rel + HD + 2 * lane);
            float rx = re.x * lre.x - im.x * lim.x;
            float ry = re.y * lre.y - im.y * lim.y;
            float ix = re.x * lim.x + im.x * lre.x;
            float iy = re.y * lim.y + im.y * lre.y;
            Arow[200 + lane] = pack_bf16x2(rx, ry);
            Arow[250 + lane] = pack_bf16x2(ix, iy);
        } else if (lane < 54) {
            Arow[300 + (lane - 50)] = 0u;
        }
    } else if (b < CE_B + CR_B) {
        int i = (b - CE_B) * 256 + tid;
        const int n4 = 2 * N_RELC * DIM / 4;   // 20000
        if (i < n4) {
            float4 v = ((const float4*)rel)[i];
            uint2 o;
            o.x = pack_bf16x2(v.x, v.y);
            o.y = pack_bf16x2(v.z, v.w);
            ((uint2*)rel16)[i] = o;
        }
    } else if (b < CE_B + CR_B + PB_B) {
        int i = (b - CE_B - CR_B) * 256 + tid;
        if (i >= 256 * KP) return;
        int c = i / KP, k = i % KP;
        float v = 0.f;
        if (c < DIM) {
            if (k < 200)      v = w_in[k * DIM + c];
            else if (k < 400) v = w_out[(k - 200) * DIM + c];
            else if (k < 600) v = w_loop[(k - 400) * DIM + c];
        }
        u32 u = __float_as_uint(v);
        u = (u + 0x7FFFu + ((u >> 16) & 1u)) >> 16;
        BT[i] = (ushort)u;
    } else {
        int i = (b - CE_B - CR_B - PB_B) * 256 + tid;
        int stride = DEG_B * 256;
        for (; i < n_edge; i += stride) {
            atomicAdd(&deg_in[dst[i]], 1);
            atomicAdd(&deg_out[src[i]], 1);
        }
    }
}

// Hierarchical scan, pass A: per-block partial sums (8 elems/thread).
__global__ __launch_bounds__(256) void scan_part_kernel(
        const int* __restrict__ deg_in, const int* __restrict__ deg_out,
        int* __restrict__ partials) {
    int dir = blockIdx.x >= SCAN_NB;
    int blk = blockIdx.x - dir * SCAN_NB;
    const int* deg = dir ? deg_out : deg_in;
    int t = threadIdx.x;
    int base = blk * SCAN_B + t * 8;
    int s = 0;
#pragma unroll
    for (int u = 0; u < 8; ++u) {
        int i = base + u;
        if (i < N_ENT) s += deg[i];
    }
    __shared__ int red[256];
    red[t] = s;
    __syncthreads();
    for (int d = 128; d > 0; d >>= 1) {
        if (t < d) red[t] += red[t + d];
        __syncthreads();
    }
    if (t == 0) partials[dir * SCAN_NB + blk] = red[0];
}

// Pass B (folded): per-block scan + base from raw partials; write off/cur/inv.
__global__ __launch_bounds__(256) void scan_apply_kernel(
        const int* __restrict__ deg_in, const int* __restrict__ deg_out,
        const int* __restrict__ partials,
        int* __restrict__ off_in, int* __restrict__ off_out,
        int* __restrict__ cur_in, int* __restrict__ cur_out,
        float* __restrict__ inv_in, float* __restrict__ inv_out) {
    int dir = blockIdx.x >= SCAN_NB;
    int blk = blockIdx.x - dir * SCAN_NB;
    const int* deg = dir ? deg_out : deg_in;
    int* off   = dir ? off_out : off_in;
    int* cur   = dir ? cur_out : cur_in;
    float* inv = dir ? inv_out : inv_in;
    int t = threadIdx.x;
    int base = blk * SCAN_B + t * 8;
    int v[8];
    int s = 0;
#pragma unroll
    for (int u = 0; u < 8; ++u) {
        int i = base + u;
        v[u] = (i < N_ENT) ? deg[i] : 0;
        s += v[u];
    }
    __shared__ int red[256];
    red[t] = s;
    __syncthreads();
    for (int d = 1; d < 256; d <<= 1) {
        int x = (t >= d) ? red[t - d] : 0;
        __syncthreads();
        red[t] += x;
        __syncthreads();
    }
    int base_off = 0;
    for (int bq = 0; bq < blk; ++bq) base_off += partials[dir * SCAN_NB + bq];
    int run = base_off + red[t] - s;
#pragma unroll
    for (int u = 0; u < 8; ++u) {
        int i = base + u;
        if (i < N_ENT) {
            off[i] = run;
            cur[i] = run;
            inv[i] = invsqrt_pos((float)v[u]);
            run += v[u];
            if (i == N_ENT - 1) off[N_ENT] = run;
        }
    }
}

// CSR fill, 8-way batched phases: 24 loads, then 16 atomics in flight,
// then 16 scattered stores. 512 blocks -> exactly 8 edges/thread.
__global__ __launch_bounds__(256) void fill_kernel(
        const int* __restrict__ src, const int* __restrict__ dst,
        const int* __restrict__ etype,
        int* cur_in, int* cur_out,
        u32* __restrict__ csr_in, u32* __restrict__ csr_out, int n) {
    int tid  = blockIdx.x * blockDim.x + threadIdx.x;
    int nthr = gridDim.x * blockDim.x;
    for (int base = tid; base < n; base += 8 * nthr) {
        int s[8], d[8], e[8];
        bool k[8];
#pragma unroll
        for (int u = 0; u < 8; ++u) {
            int i = base + u * nthr;
            k[u] = i < n;
            int ii = k[u] ? i : base;
            s[u] = src[ii]; d[u] = dst[ii]; e[u] = etype[ii];
        }
        int pi[8], po[8];
#pragma unroll
        for (int u = 0; u < 8; ++u) {
            if (k[u]) {
                pi[u] = atomicAdd(&cur_in[d[u]], 1);
                po[u] = atomicAdd(&cur_out[s[u]], 1);
            }
        }
#pragma unroll
        for (int u = 0; u < 8; ++u) {
            if (k[u]) {
                csr_in[pi[u]]  = ((u32)s[u] << 8) | (u32)e[u];
                csr_out[po[u]] = ((u32)d[u] << 8) | (u32)e[u];
            }
        }
    }
}

// One wave per node; 4 independent accumulator chains; bf16 split tables
// (r13 known-good structure, 164us).
__global__ __launch_bounds__(256) void gather_kernel(
        const ushort* __restrict__ ent16, const ushort* __restrict__ rel16,
        const u32* __restrict__ csr_in, const u32* __restrict__ csr_out,
        const int* __restrict__ off_in, const int* __restrict__ off_out,
        const float* __restrict__ inv_in, const float* __restrict__ inv_out,
        ushort* __restrict__ Abuf) {
    int node = (blockIdx.x * blockDim.x + threadIdx.x) >> 6;
    int lane = threadIdx.x & 63;
    if (node >= N_ENT) return;
    const bool act = lane < 50;
    u32* Arow = (u32*)(Abuf + (size_t)node * KP);

#pragma unroll
    for (int dir = 0; dir < 2; ++dir) {
        const u32* csr = dir ? csr_out : csr_in;
        const int* off = dir ? off_out : off_in;
        const float* inv = dir ? inv_out : inv_in;
        const int tofs = dir ? N_RELC : 0;
        float myinv = inv[node];
        float2 are = {0.f, 0.f}, aim = {0.f, 0.f};   // chain A
        float2 bre = {0.f, 0.f}, bim = {0.f, 0.f};   // chain B
        float2 cre = {0.f, 0.f}, cim = {0.f, 0.f};   // chain C
        float2 dre = {0.f, 0.f}, dim_ = {0.f, 0.f};  // chain D
        int i0 = off[node], i1 = off[node + 1];
        int i = i0;
        for (; i + 3 < i1; i += 4) {
            u32 pk0 = csr[i],     pk1 = csr[i + 1];
            u32 pk2 = csr[i + 2], pk3 = csr[i + 3];
            int s0 = (int)(pk0 >> 8), t0 = (int)(pk0 & 255u) + tofs;
            int s1 = (int)(pk1 >> 8), t1 = (int)(pk1 & 255u) + tofs;
            int s2 = (int)(pk2 >> 8), t2 = (int)(pk2 & 255u) + tofs;
            int s3 = (int)(pk3 >> 8), t3 = (int)(pk3 & 255u) + tofs;
            float n0 = myinv * inv[s0];
            float n1 = myinv * inv[s1];
            float n2 = myinv * inv[s2];
            float n3 = myinv * inv[s3];
            if (act) {
                const u32* h0 = (const u32*)(ent16 + (size_t)s0 * DIM);
                const u32* r0 = (const u32*)(rel16 + (size_t)t0 * DIM);
                const u32* h1 = (const u32*)(ent16 + (size_t)s1 * DIM);
                const u32* r1 = (const u32*)(rel16 + (size_t)t1 * DIM);
                const u32* h2 = (const u32*)(ent16 + (size_t)s2 * DIM);
                const u32* r2 = (const u32*)(rel16 + (size_t)t2 * DIM);
                const u32* h3 = (const u32*)(ent16 + (size_t)s3 * DIM);
                const u32* r3 = (const u32*)(rel16 + (size_t)t3 * DIM);
                u32 hre0 = h0[lane], him0 = h0[50 + lane];
                u32 rre0 = r0[lane], rim0 = r0[50 + lane];
                u32 hre1 = h1[lane], him1 = h1[50 + lane];
                u32 rre1 = r1[lane], rim1 = r1[50 + lane];
                u32 hre2 = h2[lane], him2 = h2[50 + lane];
                u32 rre2 = r2[lane], rim2 = r2[50 + lane];
                u32 hre3 = h3[lane], him3 = h3[50 + lane];
                u32 rre3 = r3[lane], rim3 = r3[50 + lane];
                {
                    float ha = bf_lo(hre0), hb = bf_hi(hre0);
                    float ia = bf_lo(him0), ib = bf_hi(him0);
                    float ra = bf_lo(rre0), rb = bf_hi(rre0);
                    float ja = bf_lo(rim0), jb = bf_hi(rim0);
                    are.x += (ha * ra - ia * ja) * n0;
                    are.y += (hb * rb - ib * jb) * n0;
                    aim.x += (ha * ja + ia * ra) * n0;
                    aim.y += (hb * jb + ib * rb) * n0;
                }
                {
                    float ha = bf_lo(hre1), hb = bf_hi(hre1);
                    float ia = bf_lo(him1), ib = bf_hi(him1);
                    float ra = bf_lo(rre1), rb = bf_hi(rre1);
                    float ja = bf_lo(rim1), jb = bf_hi(rim1);
                    bre.x += (ha * ra - ia * ja) * n1;
                    bre.y += (hb * rb - ib * jb) * n1;
                    bim.x += (ha * ja + ia * ra) * n1;
                    bim.y += (hb * jb + ib * rb) * n1;
                }
                {
                    float ha = bf_lo(hre2), hb = bf_hi(hre2);
                    float ia = bf_lo(him2), ib = bf_hi(him2);
                    float ra = bf_lo(rre2), rb = bf_hi(rre2);
                    float ja = bf_lo(rim2), jb = bf_hi(rim2);
                    cre.x += (ha * ra - ia * ja) * n2;
                    cre.y += (hb * rb - ib * jb) * n2;
                    cim.x += (ha * ja + ia * ra) * n2;
                    cim.y += (hb * jb + ib * rb) * n2;
                }
                {
                    float ha = bf_lo(hre3), hb = bf_hi(hre3);
                    float ia = bf_lo(him3), ib = bf_hi(him3);
                    float ra = bf_lo(rre3), rb = bf_hi(rre3);
                    float ja = bf_lo(rim3), jb = bf_hi(rim3);
                    dre.x += (ha * ra - ia * ja) * n3;
                    dre.y += (hb * rb - ib * jb) * n3;
                    dim_.x += (ha * ja + ia * ra) * n3;
                    dim_.y += (hb * jb + ib * rb) * n3;
                }
            }
        }
        for (; i < i1; ++i) {   // 0-3 remainder into chain A
            u32 pk = csr[i];
            int s = (int)(pk >> 8), t = (int)(pk & 255u) + tofs;
            float nrm = myinv * inv[s];
            if (act) {
                const u32* h32 = (const u32*)(ent16 + (size_t)s * DIM);
                const u32* r32 = (const u32*)(rel16 + (size_t)t * DIM);
                u32 hre = h32[lane], him = h32[50 + lane];
                u32 rre = r32[lane], rim = r32[50 + lane];
                float ha = bf_lo(hre), hb = bf_hi(hre);
                float ia = bf_lo(him), ib = bf_hi(him);
                float ra = bf_lo(rre), rb = bf_hi(rre);
                float ja = bf_lo(rim), jb = bf_hi(rim);
                are.x += (ha * ra - ia * ja) * nrm;
                are.y += (hb * rb - ib * jb) * nrm;
                aim.x += (ha * ja + ia * ra) * nrm;
                aim.y += (hb * jb + ib * rb) * nrm;
            }
        }
        if (act) {
            are.x += bre.x + cre.x + dre.x;
            are.y += bre.y + cre.y + dre.y;
            aim.x += bim.x + cim.x + dim_.x;
            aim.y += bim.y + cim.y + dim_.y;
            Arow[dir * 100 + lane]      = pack_bf16x2(are.x, are.y);
            Arow[dir * 100 + 50 + lane] = pack_bf16x2(aim.x, aim.y);
        }
    }
}

// C = A(MPADxKP) @ BT^T -> pre (f32)*1/3 + bias; fused BN column stats.
// r13 known-good: A and B both double-buffered in LDS via global_load_lds.
__global__ __launch_bounds__(512, 4) void gemm_kernel(
        const ushort* __restrict__ A, const ushort* __restrict__ BT,
        const float* __restrict__ bias, float* __restrict__ out,
        float* __restrict__ stats) {
    __shared__ ushort Asm[2][BM * 32];
    __shared__ ushort Bsm[2][BNN * 32];
    __shared__ float sredS[8][4][16];
    __shared__ float sredQ[8][4][16];
    const int tid = threadIdx.x;
    const int row0 = blockIdx.x * BM;
    const int l = tid & 63;
    const int w = tid >> 6;
    const int wm = w >> 2;
    const int wn = w & 3;

    f32x4 acc[4][4];
#pragma unroll
    for (int i = 0; i < 4; ++i)
#pragma unroll
        for (int j = 0; j < 4; ++j)
            acc[i][j] = (f32x4){0.f, 0.f, 0.f, 0.f};

    {
        int r = tid >> 2, s = tid & 3;
        lds_cp16(&Asm[0][tid * 8], A + (size_t)(row0 + r) * KP + s * 8);
#pragma unroll
        for (int j = 0; j < 2; ++j) {
            int c = tid + j * 512;
            int br = c >> 2, bs = c & 3;
            lds_cp16(&Bsm[0][c * 8], BT + (size_t)br * KP + bs * 8);
        }
    }

    int cur = 0;
    for (int ks = 0; ks < NT; ++ks) {
        __syncthreads();
        if (ks + 1 < NT) {
            const int k0 = (ks + 1) * 32;
            int r = tid >> 2, s = tid & 3;
            lds_cp16(&Asm[cur ^ 1][tid * 8], A + (size_t)(row0 + r) * KP + k0 + s * 8);
#pragma unroll
            for (int j = 0; j < 2; ++j) {
                int c = tid + j * 512;
                int br = c >> 2, bs = c & 3;
                lds_cp16(&Bsm[cur ^ 1][c * 8], BT + (size_t)br * KP + k0 + bs * 8);
            }
        }
        const int kq = (l >> 4) * 8;
        const int lr = l & 15;
        bf16x8 aF[4], bF[4];
#pragma unroll
        for (int mf = 0; mf < 4; ++mf)
            aF[mf] = *(const bf16x8*)&Asm[cur][(wm * 64 + mf * 16 + lr) * 32 + kq];
#pragma unroll
        for (int nf = 0; nf < 4; ++nf)
            bF[nf] = *(const bf16x8*)&Bsm[cur][(wn * 64 + nf * 16 + lr) * 32 + kq];
#pragma unroll
        for (int mf = 0; mf < 4; ++mf)
#pragma unroll
            for (int nf = 0; nf < 4; ++nf)
                acc[mf][nf] = __builtin_amdgcn_mfma_f32_16x16x32_bf16(
                        aF[mf], bF[nf], acc[mf][nf], 0, 0, 0);
        cur ^= 1;
    }

    const int lr = l & 15;
    const int rq = (l >> 4) * 4;
    float colS[4], colQ[4];
#pragma unroll
    for (int nf = 0; nf < 4; ++nf) { colS[nf] = 0.f; colQ[nf] = 0.f; }

#pragma unroll
    for (int nf = 0; nf < 4; ++nf) {
        int gcol = wn * 64 + nf * 16 + lr;
        bool cok = gcol < DIM;
        float b = cok ? bias[gcol] : 0.f;
#pragma unroll
        for (int mf = 0; mf < 4; ++mf) {
            int grow0 = row0 + wm * 64 + mf * 16 + rq;
#pragma unroll
            for (int r = 0; r < 4; ++r) {
                int grow = grow0 + r;
                if (grow < N_ENT && cok) {
                    float v = acc[mf][nf][r] * (1.f / 3.f) + b;
                    out[(size_t)grow * DIM + gcol] = v;
                    colS[nf] += v;
                    colQ[nf] += v * v;
                }
            }
        }
    }
#pragma unroll
    for (int nf = 0; nf < 4; ++nf) {
        colS[nf] += __shfl_down(colS[nf], 32);
        colS[nf] += __shfl_down(colS[nf], 16);
        colQ[nf] += __shfl_down(colQ[nf], 32);
        colQ[nf] += __shfl_down(colQ[nf], 16);
    }
    if (l < 16) {
#pragma unroll
        for (int nf = 0; nf < 4; ++nf) {
            sredS[w][nf][l] = colS[nf];
            sredQ[w][nf][l] = colQ[nf];
        }
    }
    __syncthreads();
    if (tid < DIM) {
        int wn_ = tid >> 6, nf_ = (tid >> 4) & 3, lr_ = tid & 15;
        float s = sredS[wn_][nf_][lr_] + sredS[wn_ + 4][nf_][lr_];
        float q = sredQ[wn_][nf_][lr_] + sredQ[wn_ + 4][nf_][lr_];
        atomicAdd(&stats[tid], s);
        atomicAdd(&stats[DIM + tid], q);
    }
}

// BN finalize + tanh; scale/shift derived from stats per block.
__global__ __launch_bounds__(256) void bn_tanh_kernel(
        float* __restrict__ out, const float* __restrict__ stats,
        const float* __restrict__ gamma, const float* __restrict__ beta) {
    __shared__ float ssc[DIM], ssh[DIM];
    int t = threadIdx.x;
    if (t < DIM) {
        float mean = stats[t] * (1.f / (float)N_ENT);
        float var  = stats[DIM + t] * (1.f / (float)N_ENT) - mean * mean;
        float scale = gamma[t] / sqrtf(var + 1e-5f);
        ssc[t] = scale;
        ssh[t] = beta[t] - mean * scale;
    }
    __syncthreads();
    size_t i = (size_t)blockIdx.x * blockDim.x + threadIdx.x;
    size_t stride = (size_t)gridDim.x * blockDim.x;
    const size_t n4 = (size_t)N_ENT * DIM / 4;
    float4* p = (float4*)out;
    for (; i < n4; i += stride) {
        int c = (int)((i * 4) % DIM);
        float4 v = p[i];
        v.x = tanhf(v.x * ssc[c]     + ssh[c]);
        v.y = tanhf(v.y * ssc[c + 1] + ssh[c + 1]);
        v.z = tanhf(v.z * ssc[c + 2] + ssh[c + 2]);
        v.w = tanhf(v.w * ssc[c + 3] + ssh[c + 3]);
        p[i] = v;
    }
}

extern "C" void kernel_launch(void* const* d_in, const int* in_sizes, int n_in,
                              void* d_out, int out_size, void* d_ws, size_t ws_size,
                              hipStream_t stream) {
    const float* ent      = (const float*)d_in[0];
    const float* rel      = (const float*)d_in[1];
    const float* loop_rel = (const float*)d_in[2];
    const float* w_in     = (const float*)d_in[3];
    const float* w_out    = (const float*)d_in[4];
    const float* w_loop   = (const float*)d_in[5];
    const float* bias     = (const float*)d_in[6];
    const float* gamma    = (const float*)d_in[7];
    const float* beta     = (const float*)d_in[8];
    const int*   eidx     = (const int*)d_in[9];
    const int*   etype    = (const int*)d_in[10];
    const int n_edge = in_sizes[10];
    const int* src = eidx;
    const int* dst = eidx + n_edge;

    // workspace layout
    ushort* Abuf   = (ushort*)d_ws;                        // MPAD*KP bf16 (121.7MB)
    ushort* BT     = Abuf + (size_t)MPAD * KP;             // 256*KP bf16
    int* deg_in    = (int*)(BT + 256 * KP);
    int* deg_out   = deg_in + N_ENT;
    int* off_in    = deg_out + N_ENT;
    int* off_out   = off_in + N_ENT + 1;
    int* cur_in    = off_out + N_ENT + 1;
    int* cur_out   = cur_in + N_ENT;
    float* inv_in  = (float*)(cur_out + N_ENT);
    float* inv_out = inv_in + N_ENT;
    int* partials  = (int*)(inv_out + N_ENT);              // 2*SCAN_NB
    u32* csr_in    = (u32*)(partials + 2 * SCAN_NB);       // n_edge
    u32* csr_out   = csr_in + n_edge;                      // n_edge
    float* stats   = (float*)(csr_out + n_edge);           // 2*DIM
    ushort* rel16  = (ushort*)(stats + 2 * DIM);           // 2*N_RELC*DIM bf16
    float* outp    = (float*)d_out;
    // bf16 entity table lives in d_out (dead until gemm writes it)
    ushort* ent16  = (ushort*)d_out;                       // 40MB

    hipMemsetAsync(deg_in, 0, (size_t)2 * N_ENT * sizeof(int), stream);
    hipMemsetAsync(stats, 0, (size_t)2 * DIM * sizeof(float), stream);

    prep_kernel<<<CE_B + CR_B + PB_B + DEG_B, 256, 0, stream>>>(
        ent, rel, loop_rel, w_in, w_out, w_loop, src, dst,
        ent16, rel16, BT, Abuf, deg_in, deg_out, n_edge);
    scan_part_kernel<<<2 * SCAN_NB, 256, 0, stream>>>(deg_in, deg_out, partials);
    scan_apply_kernel<<<2 * SCAN_NB, 256, 0, stream>>>(
        deg_in, deg_out, partials, off_in, off_out, cur_in, cur_out,
        inv_in, inv_out);
    fill_kernel<<<512, 256, 0, stream>>>(src, dst, etype, cur_in, cur_out,
                                         csr_in, csr_out, n_edge);
    gather_kernel<<<25000, 256, 0, stream>>>(ent16, rel16, csr_in, csr_out,
                                             off_in, off_out, inv_in, inv_out, Abuf);
    gemm_kernel<<<MPAD / BM, 512, 0, stream>>>(Abuf, BT, bias, outp, stats);
    bn_tanh_kernel<<<2048, 256, 0, stream>>>(outp, stats, gamma, beta);
}

// Round 18
// 504.840 us; speedup vs baseline: 1.1193x; 1.0535x over previous
//
#include <hip/hip_runtime.h>
#include <math.h>
#include <stdint.h>

#define N_ENT   100000
#define DIM     200
#define HD      100       // DIM/2
#define N_RELC  200
#define KP      608       // padded K: 3*200 -> 19*32
#define BM      128
#define BNN     256       // padded N (200 -> 256)
#define NT      19        // K steps of 32
#define MPAD    100096    // 782 * 128
#define SCAN_B  2048
#define SCAN_NB 49        // ceil(N_ENT / SCAN_B)

// fused prep kernel block ranges
#define CE_B    25000     // conv_ent: 4 rows/block
#define CR_B    100       // conv_rel elementwise
#define PB_B    608       // prep_bt
#define DEG_B   1024      // deg grid-stride

typedef uint32_t u32;
typedef __attribute__((ext_vector_type(8))) short bf16x8;
typedef __attribute__((ext_vector_type(4))) float f32x4;

__device__ __forceinline__ float invsqrt_pos(float x) {
    return x > 0.f ? (1.f / sqrtf(x)) : 0.f;
}

__device__ __forceinline__ u32 pack_bf16x2(float a, float b) {
    u32 ua = __float_as_uint(a), ub = __float_as_uint(b);
    ua = (ua + 0x7FFFu + ((ua >> 16) & 1u)) >> 16;
    ub = (ub + 0x7FFFu + ((ub >> 16) & 1u)) >> 16;
    return ua | (ub << 16);
}

__device__ __forceinline__ float bf_lo(u32 u) { return __uint_as_float(u << 16); }
__device__ __forceinline__ float bf_hi(u32 u) { return __uint_as_float(u & 0xFFFF0000u); }

// global -> LDS direct copy, 16B per lane (dest must be linear in lane id)
__device__ __forceinline__ void lds_cp16(void* lds, const void* g) {
    auto gp = (const __attribute__((address_space(1))) u32*)(uintptr_t)g;
    auto lp = (__attribute__((address_space(3))) u32*)(u32)(uintptr_t)lds;
    __builtin_amdgcn_global_load_lds(gp, lp, 16, 0, 0);
}

// Fused prep: conv_ent | conv_rel | prep_bt | deg, role by blockIdx.
__global__ __launch_bounds__(256) void prep_kernel(
        const float* __restrict__ ent, const float* __restrict__ rel,
        const float* __restrict__ loop_rel,
        const float* __restrict__ w_in, const float* __restrict__ w_out,
        const float* __restrict__ w_loop,
        const int* __restrict__ src, const int* __restrict__ dst,
        ushort* __restrict__ ent16, ushort* __restrict__ rel16,
        ushort* __restrict__ BT, ushort* __restrict__ Abuf,
        int* __restrict__ deg_in, int* __restrict__ deg_out, int n_edge) {
    const int b = blockIdx.x;
    const int tid = threadIdx.x;
    if (b < CE_B) {
        int row  = (b * 256 + tid) >> 6;
        int lane = tid & 63;
        if (row >= N_ENT) return;
        u32* Arow = (u32*)(Abuf + (size_t)row * KP);
        if (lane < 50) {
            const float* h = ent + (size_t)row * DIM;
            float2 re = *(const float2*)(h + 2 * lane);
            float2 im = *(const float2*)(h + HD + 2 * lane);
            u32* e32 = (u32*)(ent16 + (size_t)row * DIM);
            e32[lane]      = pack_bf16x2(re.x, re.y);
            e32[50 + lane] = pack_bf16x2(im.x, im.y);
            float2 lre = *(const float2*)(loop_rel + 2 * lane);
            float2 lim = *(const float2*)(loop_rel + HD + 2 * lane);
            float rx = re.x * lre.x - im.x * lim.x;
            float ry = re.y * lre.y - im.y * lim.y;
            float ix = re.x * lim.x + im.x * lre.x;
            float iy = re.y * lim.y + im.y * lre.y;
            Arow[200 + lane] = pack_bf16x2(rx, ry);
            Arow[250 + lane] = pack_bf16x2(ix, iy);
        } else if (lane < 54) {
            Arow[300 + (lane - 50)] = 0u;
        }
    } else if (b < CE_B + CR_B) {
        int i = (b - CE_B) * 256 + tid;
        const int n4 = 2 * N_RELC * DIM / 4;   // 20000
        if (i < n4) {
            float4 v = ((const float4*)rel)[i];
            uint2 o;
            o.x = pack_bf16x2(v.x, v.y);
            o.y = pack_bf16x2(v.z, v.w);
            ((uint2*)rel16)[i] = o;
        }
    } else if (b < CE_B + CR_B + PB_B) {
        int i = (b - CE_B - CR_B) * 256 + tid;
        if (i >= 256 * KP) return;
        int c = i / KP, k = i % KP;
        float v = 0.f;
        if (c < DIM) {
            if (k < 200)      v = w_in[k * DIM + c];
            else if (k < 400) v = w_out[(k - 200) * DIM + c];
            else if (k < 600) v = w_loop[(k - 400) * DIM + c];
        }
        u32 u = __float_as_uint(v);
        u = (u + 0x7FFFu + ((u >> 16) & 1u)) >> 16;
        BT[i] = (ushort)u;
    } else {
        int i = (b - CE_B - CR_B - PB_B) * 256 + tid;
        int stride = DEG_B * 256;
        for (; i < n_edge; i += stride) {
            atomicAdd(&deg_in[dst[i]], 1);
            atomicAdd(&deg_out[src[i]], 1);
        }
    }
}

// Hierarchical scan, pass A: per-block partial sums (8 elems/thread).
__global__ __launch_bounds__(256) void scan_part_kernel(
        const int* __restrict__ deg_in, const int* __restrict__ deg_out,
        int* __restrict__ partials) {
    int dir = blockIdx.x >= SCAN_NB;
    int blk = blockIdx.x - dir * SCAN_NB;
    const int* deg = dir ? deg_out : deg_in;
    int t = threadIdx.x;
    int base = blk * SCAN_B + t * 8;
    int s = 0;
#pragma unroll
    for (int u = 0; u < 8; ++u) {
        int i = base + u;
        if (i < N_ENT) s += deg[i];
    }
    __shared__ int red[256];
    red[t] = s;
    __syncthreads();
    for (int d = 128; d > 0; d >>= 1) {
        if (t < d) red[t] += red[t + d];
        __syncthreads();
    }
    if (t == 0) partials[dir * SCAN_NB + blk] = red[0];
}

// Pass B (folded): per-block scan + base from raw partials; write off/cur/inv.
__global__ __launch_bounds__(256) void scan_apply_kernel(
        const int* __restrict__ deg_in, const int* __restrict__ deg_out,
        const int* __restrict__ partials,
        int* __restrict__ off_in, int* __restrict__ off_out,
        int* __restrict__ cur_in, int* __restrict__ cur_out,
        float* __restrict__ inv_in, float* __restrict__ inv_out) {
    int dir = blockIdx.x >= SCAN_NB;
    int blk = blockIdx.x - dir * SCAN_NB;
    const int* deg = dir ? deg_out : deg_in;
    int* off   = dir ? off_out : off_in;
    int* cur   = dir ? cur_out : cur_in;
    float* inv = dir ? inv_out : inv_in;
    int t = threadIdx.x;
    int base = blk * SCAN_B + t * 8;
    int v[8];
    int s = 0;
#pragma unroll
    for (int u = 0; u < 8; ++u) {
        int i = base + u;
        v[u] = (i < N_ENT) ? deg[i] : 0;
        s += v[u];
    }
    __shared__ int red[256];
    red[t] = s;
    __syncthreads();
    for (int d = 1; d < 256; d <<= 1) {
        int x = (t >= d) ? red[t - d] : 0;
        __syncthreads();
        red[t] += x;
        __syncthreads();
    }
    int base_off = 0;
    for (int bq = 0; bq < blk; ++bq) base_off += partials[dir * SCAN_NB + bq];
    int run = base_off + red[t] - s;
#pragma unroll
    for (int u = 0; u < 8; ++u) {
        int i = base + u;
        if (i < N_ENT) {
            off[i] = run;
            cur[i] = run;
            inv[i] = invsqrt_pos((float)v[u]);
            run += v[u];
            if (i == N_ENT - 1) off[N_ENT] = run;
        }
    }
}

// CSR fill, 4-way batched phases (loads / inv loads / atomics / stores).
// Entry = uint2 { (nbr<<8)|etype, norm_f32_bits }: norm computed here so
// the gather's per-edge dependent inv[s] load disappears.
__global__ __launch_bounds__(256) void fill_kernel(
        const int* __restrict__ src, const int* __restrict__ dst,
        const int* __restrict__ etype,
        const float* __restrict__ inv_in, const float* __restrict__ inv_out,
        int* cur_in, int* cur_out,
        uint2* __restrict__ csr2_in, uint2* __restrict__ csr2_out, int n) {
    int tid  = blockIdx.x * blockDim.x + threadIdx.x;
    int nthr = gridDim.x * blockDim.x;
    for (int base = tid; base < n; base += 4 * nthr) {
        int i0 = base;
        int i1 = base + nthr;
        int i2 = base + 2 * nthr;
        int i3 = base + 3 * nthr;
        bool k1 = i1 < n, k2 = i2 < n, k3 = i3 < n;
        // phase 1: coalesced meta loads
        int s0 = src[i0], d0 = dst[i0], e0 = etype[i0];
        int s1 = 0, d1 = 0, e1 = 0, s2 = 0, d2 = 0, e2 = 0, s3 = 0, d3 = 0, e3 = 0;
        if (k1) { s1 = src[i1]; d1 = dst[i1]; e1 = etype[i1]; }
        if (k2) { s2 = src[i2]; d2 = dst[i2]; e2 = etype[i2]; }
        if (k3) { s3 = src[i3]; d3 = dst[i3]; e3 = etype[i3]; }
        // phase 1b: independent inv loads (L2-resident 400KB tables)
        float ni0 = inv_in[d0] * inv_in[s0];
        float no0 = inv_out[s0] * inv_out[d0];
        float ni1 = 0.f, no1 = 0.f, ni2 = 0.f, no2 = 0.f, ni3 = 0.f, no3 = 0.f;
        if (k1) { ni1 = inv_in[d1] * inv_in[s1]; no1 = inv_out[s1] * inv_out[d1]; }
        if (k2) { ni2 = inv_in[d2] * inv_in[s2]; no2 = inv_out[s2] * inv_out[d2]; }
        if (k3) { ni3 = inv_in[d3] * inv_in[s3]; no3 = inv_out[s3] * inv_out[d3]; }
        // phase 2: all atomics issued before any result is consumed
        int pi0 = atomicAdd(&cur_in[d0], 1);
        int po0 = atomicAdd(&cur_out[s0], 1);
        int pi1 = 0, po1 = 0, pi2 = 0, po2 = 0, pi3 = 0, po3 = 0;
        if (k1) { pi1 = atomicAdd(&cur_in[d1], 1); po1 = atomicAdd(&cur_out[s1], 1); }
        if (k2) { pi2 = atomicAdd(&cur_in[d2], 1); po2 = atomicAdd(&cur_out[s2], 1); }
        if (k3) { pi3 = atomicAdd(&cur_in[d3], 1); po3 = atomicAdd(&cur_out[s3], 1); }
        // phase 3: scattered stores
        csr2_in[pi0]  = make_uint2(((u32)s0 << 8) | (u32)e0, __float_as_uint(ni0));
        csr2_out[po0] = make_uint2(((u32)d0 << 8) | (u32)e0, __float_as_uint(no0));
        if (k1) { csr2_in[pi1]  = make_uint2(((u32)s1 << 8) | (u32)e1, __float_as_uint(ni1));
                  csr2_out[po1] = make_uint2(((u32)d1 << 8) | (u32)e1, __float_as_uint(no1)); }
        if (k2) { csr2_in[pi2]  = make_uint2(((u32)s2 << 8) | (u32)e2, __float_as_uint(ni2));
                  csr2_out[po2] = make_uint2(((u32)d2 << 8) | (u32)e2, __float_as_uint(no2)); }
        if (k3) { csr2_in[pi3]  = make_uint2(((u32)s3 << 8) | (u32)e3, __float_as_uint(ni3));
                  csr2_out[po3] = make_uint2(((u32)d3 << 8) | (u32)e3, __float_as_uint(no3)); }
    }
}

// One wave per node; 4 independent accumulator chains; bf16 split tables.
// Norm comes packed with the CSR entry (no per-edge inv gathers).
__global__ __launch_bounds__(256) void gather_kernel(
        const ushort* __restrict__ ent16, const ushort* __restrict__ rel16,
        const uint2* __restrict__ csr2_in, const uint2* __restrict__ csr2_out,
        const int* __restrict__ off_in, const int* __restrict__ off_out,
        ushort* __restrict__ Abuf) {
    int node = (blockIdx.x * blockDim.x + threadIdx.x) >> 6;
    int lane = threadIdx.x & 63;
    if (node >= N_ENT) return;
    const bool act = lane < 50;
    u32* Arow = (u32*)(Abuf + (size_t)node * KP);

#pragma unroll
    for (int dir = 0; dir < 2; ++dir) {
        const uint2* csr = dir ? csr2_out : csr2_in;
        const int* off = dir ? off_out : off_in;
        const int tofs = dir ? N_RELC : 0;
        float2 are = {0.f, 0.f}, aim = {0.f, 0.f};   // chain A
        float2 bre = {0.f, 0.f}, bim = {0.f, 0.f};   // chain B
        float2 cre = {0.f, 0.f}, cim = {0.f, 0.f};   // chain C
        float2 dre = {0.f, 0.f}, dim_ = {0.f, 0.f};  // chain D
        int i0 = off[node], i1 = off[node + 1];
        int i = i0;
        for (; i + 3 < i1; i += 4) {
            uint2 pk0 = csr[i],     pk1 = csr[i + 1];
            uint2 pk2 = csr[i + 2], pk3 = csr[i + 3];
            int s0 = (int)(pk0.x >> 8), t0 = (int)(pk0.x & 255u) + tofs;
            int s1 = (int)(pk1.x >> 8), t1 = (int)(pk1.x & 255u) + tofs;
            int s2 = (int)(pk2.x >> 8), t2 = (int)(pk2.x & 255u) + tofs;
            int s3 = (int)(pk3.x >> 8), t3 = (int)(pk3.x & 255u) + tofs;
            float n0 = __uint_as_float(pk0.y);
            float n1 = __uint_as_float(pk1.y);
            float n2 = __uint_as_float(pk2.y);
            float n3 = __uint_as_float(pk3.y);
            if (act) {
                const u32* h0 = (const u32*)(ent16 + (size_t)s0 * DIM);
                const u32* r0 = (const u32*)(rel16 + (size_t)t0 * DIM);
                const u32* h1 = (const u32*)(ent16 + (size_t)s1 * DIM);
                const u32* r1 = (const u32*)(rel16 + (size_t)t1 * DIM);
                const u32* h2 = (const u32*)(ent16 + (size_t)s2 * DIM);
                const u32* r2 = (const u32*)(rel16 + (size_t)t2 * DIM);
                const u32* h3 = (const u32*)(ent16 + (size_t)s3 * DIM);
                const u32* r3 = (const u32*)(rel16 + (size_t)t3 * DIM);
                u32 hre0 = h0[lane], him0 = h0[50 + lane];
                u32 rre0 = r0[lane], rim0 = r0[50 + lane];
                u32 hre1 = h1[lane], him1 = h1[50 + lane];
                u32 rre1 = r1[lane], rim1 = r1[50 + lane];
                u32 hre2 = h2[lane], him2 = h2[50 + lane];
                u32 rre2 = r2[lane], rim2 = r2[50 + lane];
                u32 hre3 = h3[lane], him3 = h3[50 + lane];
                u32 rre3 = r3[lane], rim3 = r3[50 + lane];
                {
                    float ha = bf_lo(hre0), hb = bf_hi(hre0);
                    float ia = bf_lo(him0), ib = bf_hi(him0);
                    float ra = bf_lo(rre0), rb = bf_hi(rre0);
                    float ja = bf_lo(rim0), jb = bf_hi(rim0);
                    are.x += (ha * ra - ia * ja) * n0;
                    are.y += (hb * rb - ib * jb) * n0;
                    aim.x += (ha * ja + ia * ra) * n0;
                    aim.y += (hb * jb + ib * rb) * n0;
                }
                {
                    float ha = bf_lo(hre1), hb = bf_hi(hre1);
                    float ia = bf_lo(him1), ib = bf_hi(him1);
                    float ra = bf_lo(rre1), rb = bf_hi(rre1);
                    float ja = bf_lo(rim1), jb = bf_hi(rim1);
                    bre.x += (ha * ra - ia * ja) * n1;
                    bre.y += (hb * rb - ib * jb) * n1;
                    bim.x += (ha * ja + ia * ra) * n1;
                    bim.y += (hb * jb + ib * rb) * n1;
                }
                {
                    float ha = bf_lo(hre2), hb = bf_hi(hre2);
                    float ia = bf_lo(him2), ib = bf_hi(him2);
                    float ra = bf_lo(rre2), rb = bf_hi(rre2);
                    float ja = bf_lo(rim2), jb = bf_hi(rim2);
                    cre.x += (ha * ra - ia * ja) * n2;
                    cre.y += (hb * rb - ib * jb) * n2;
                    cim.x += (ha * ja + ia * ra) * n2;
                    cim.y += (hb * jb + ib * rb) * n2;
                }
                {
                    float ha = bf_lo(hre3), hb = bf_hi(hre3);
                    float ia = bf_lo(him3), ib = bf_hi(him3);
                    float ra = bf_lo(rre3), rb = bf_hi(rre3);
                    float ja = bf_lo(rim3), jb = bf_hi(rim3);
                    dre.x += (ha * ra - ia * ja) * n3;
                    dre.y += (hb * rb - ib * jb) * n3;
                    dim_.x += (ha * ja + ia * ra) * n3;
                    dim_.y += (hb * jb + ib * rb) * n3;
                }
            }
        }
        for (; i < i1; ++i) {   // 0-3 remainder into chain A
            uint2 pk = csr[i];
            int s = (int)(pk.x >> 8), t = (int)(pk.x & 255u) + tofs;
            float nrm = __uint_as_float(pk.y);
            if (act) {
                const u32* h32 = (const u32*)(ent16 + (size_t)s * DIM);
                const u32* r32 = (const u32*)(rel16 + (size_t)t * DIM);
                u32 hre = h32[lane], him = h32[50 + lane];
                u32 rre = r32[lane], rim = r32[50 + lane];
                float ha = bf_lo(hre), hb = bf_hi(hre);
                float ia = bf_lo(him), ib = bf_hi(him);
                float ra = bf_lo(rre), rb = bf_hi(rre);
                float ja = bf_lo(rim), jb = bf_hi(rim);
                are.x += (ha * ra - ia * ja) * nrm;
                are.y += (hb * rb - ib * jb) * nrm;
                aim.x += (ha * ja + ia * ra) * nrm;
                aim.y += (hb * jb + ib * rb) * nrm;
            }
        }
        if (act) {
            are.x += bre.x + cre.x + dre.x;
            are.y += bre.y + cre.y + dre.y;
            aim.x += bim.x + cim.x + dim_.x;
            aim.y += bim.y + cim.y + dim_.y;
            Arow[dir * 100 + lane]      = pack_bf16x2(are.x, are.y);
            Arow[dir * 100 + 50 + lane] = pack_bf16x2(aim.x, aim.y);
        }
    }
}

// C = A(MPADxKP) @ BT^T -> pre (f32)*1/3 + bias; fused BN column stats.
// r13 known-good: A and B double-buffered in LDS via global_load_lds.
__global__ __launch_bounds__(512, 4) void gemm_kernel(
        const ushort* __restrict__ A, const ushort* __restrict__ BT,
        const float* __restrict__ bias, float* __restrict__ out,
        float* __restrict__ stats) {
    __shared__ ushort Asm[2][BM * 32];
    __shared__ ushort Bsm[2][BNN * 32];
    __shared__ float sredS[8][4][16];
    __shared__ float sredQ[8][4][16];
    const int tid = threadIdx.x;
    const int row0 = blockIdx.x * BM;
    const int l = tid & 63;
    const int w = tid >> 6;
    const int wm = w >> 2;
    const int wn = w & 3;

    f32x4 acc[4][4];
#pragma unroll
    for (int i = 0; i < 4; ++i)
#pragma unroll
        for (int j = 0; j < 4; ++j)
            acc[i][j] = (f32x4){0.f, 0.f, 0.f, 0.f};

    {
        int r = tid >> 2, s = tid & 3;
        lds_cp16(&Asm[0][tid * 8], A + (size_t)(row0 + r) * KP + s * 8);
#pragma unroll
        for (int j = 0; j < 2; ++j) {
            int c = tid + j * 512;
            int br = c >> 2, bs = c & 3;
            lds_cp16(&Bsm[0][c * 8], BT + (size_t)br * KP + bs * 8);
        }
    }

    int cur = 0;
    for (int ks = 0; ks < NT; ++ks) {
        __syncthreads();
        if (ks + 1 < NT) {
            const int k0 = (ks + 1) * 32;
            int r = tid >> 2, s = tid & 3;
            lds_cp16(&Asm[cur ^ 1][tid * 8], A + (size_t)(row0 + r) * KP + k0 + s * 8);
#pragma unroll
            for (int j = 0; j < 2; ++j) {
                int c = tid + j * 512;
                int br = c >> 2, bs = c & 3;
                lds_cp16(&Bsm[cur ^ 1][c * 8], BT + (size_t)br * KP + k0 + bs * 8);
            }
        }
        const int kq = (l >> 4) * 8;
        const int lr = l & 15;
        bf16x8 aF[4], bF[4];
#pragma unroll
        for (int mf = 0; mf < 4; ++mf)
            aF[mf] = *(const bf16x8*)&Asm[cur][(wm * 64 + mf * 16 + lr) * 32 + kq];
#pragma unroll
        for (int nf = 0; nf < 4; ++nf)
            bF[nf] = *(const bf16x8*)&Bsm[cur][(wn * 64 + nf * 16 + lr) * 32 + kq];
#pragma unroll
        for (int mf = 0; mf < 4; ++mf)
#pragma unroll
            for (int nf = 0; nf < 4; ++nf)
                acc[mf][nf] = __builtin_amdgcn_mfma_f32_16x16x32_bf16(
                        aF[mf], bF[nf], acc[mf][nf], 0, 0, 0);
        cur ^= 1;
    }

    const int lr = l & 15;
    const int rq = (l >> 4) * 4;
    float colS[4], colQ[4];
#pragma unroll
    for (int nf = 0; nf < 4; ++nf) { colS[nf] = 0.f; colQ[nf] = 0.f; }

#pragma unroll
    for (int nf = 0; nf < 4; ++nf) {
        int gcol = wn * 64 + nf * 16 + lr;
        bool cok = gcol < DIM;
        float b = cok ? bias[gcol] : 0.f;
#pragma unroll
        for (int mf = 0; mf < 4; ++mf) {
            int grow0 = row0 + wm * 64 + mf * 16 + rq;
#pragma unroll
            for (int r = 0; r < 4; ++r) {
                int grow = grow0 + r;
                if (grow < N_ENT && cok) {
                    float v = acc[mf][nf][r] * (1.f / 3.f) + b;
                    out[(size_t)grow * DIM + gcol] = v;
                    colS[nf] += v;
                    colQ[nf] += v * v;
                }
            }
        }
    }
#pragma unroll
    for (int nf = 0; nf < 4; ++nf) {
        colS[nf] += __shfl_down(colS[nf], 32);
        colS[nf] += __shfl_down(colS[nf], 16);
        colQ[nf] += __shfl_down(colQ[nf], 32);
        colQ[nf] += __shfl_down(colQ[nf], 16);
    }
    if (l < 16) {
#pragma unroll
        for (int nf = 0; nf < 4; ++nf) {
            sredS[w][nf][l] = colS[nf];
            sredQ[w][nf][l] = colQ[nf];
        }
    }
    __syncthreads();
    if (tid < DIM) {
        int wn_ = tid >> 6, nf_ = (tid >> 4) & 3, lr_ = tid & 15;
        float s = sredS[wn_][nf_][lr_] + sredS[wn_ + 4][nf_][lr_];
        float q = sredQ[wn_][nf_][lr_] + sredQ[wn_ + 4][nf_][lr_];
        atomicAdd(&stats[tid], s);
        atomicAdd(&stats[DIM + tid], q);
    }
}

// BN finalize + tanh; scale/shift derived from stats per block.
__global__ __launch_bounds__(256) void bn_tanh_kernel(
        float* __restrict__ out, const float* __restrict__ stats,
        const float* __restrict__ gamma, const float* __restrict__ beta) {
    __shared__ float ssc[DIM], ssh[DIM];
    int t = threadIdx.x;
    if (t < DIM) {
        float mean = stats[t] * (1.f / (float)N_ENT);
        float var  = stats[DIM + t] * (1.f / (float)N_ENT) - mean * mean;
        float scale = gamma[t] / sqrtf(var + 1e-5f);
        ssc[t] = scale;
        ssh[t] = beta[t] - mean * scale;
    }
    __syncthreads();
    size_t i = (size_t)blockIdx.x * blockDim.x + threadIdx.x;
    size_t stride = (size_t)gridDim.x * blockDim.x;
    const size_t n4 = (size_t)N_ENT * DIM / 4;
    float4* p = (float4*)out;
    for (; i < n4; i += stride) {
        int c = (int)((i * 4) % DIM);
        float4 v = p[i];
        v.x = tanhf(v.x * ssc[c]     + ssh[c]);
        v.y = tanhf(v.y * ssc[c + 1] + ssh[c + 1]);
        v.z = tanhf(v.z * ssc[c + 2] + ssh[c + 2]);
        v.w = tanhf(v.w * ssc[c + 3] + ssh[c + 3]);
        p[i] = v;
    }
}

extern "C" void kernel_launch(void* const* d_in, const int* in_sizes, int n_in,
                              void* d_out, int out_size, void* d_ws, size_t ws_size,
                              hipStream_t stream) {
    const float* ent      = (const float*)d_in[0];
    const float* rel      = (const float*)d_in[1];
    const float* loop_rel = (const float*)d_in[2];
    const float* w_in     = (const float*)d_in[3];
    const float* w_out    = (const float*)d_in[4];
    const float* w_loop   = (const float*)d_in[5];
    const float* bias     = (const float*)d_in[6];
    const float* gamma    = (const float*)d_in[7];
    const float* beta     = (const float*)d_in[8];
    const int*   eidx     = (const int*)d_in[9];
    const int*   etype    = (const int*)d_in[10];
    const int n_edge = in_sizes[10];
    const int* src = eidx;
    const int* dst = eidx + n_edge;

    // workspace layout
    ushort* Abuf   = (ushort*)d_ws;                        // MPAD*KP bf16 (121.7MB)
    ushort* BT     = Abuf + (size_t)MPAD * KP;             // 256*KP bf16
    int* deg_in    = (int*)(BT + 256 * KP);
    int* deg_out   = deg_in + N_ENT;
    int* off_in    = deg_out + N_ENT;
    int* off_out   = off_in + N_ENT + 1;
    int* cur_in    = off_out + N_ENT + 1;
    int* cur_out   = cur_in + N_ENT;
    float* inv_in  = (float*)(cur_out + N_ENT);
    float* inv_out = inv_in + N_ENT;
    int* partials  = (int*)(inv_out + N_ENT);              // 2*SCAN_NB
    float* stats   = (float*)(partials + 2 * SCAN_NB);     // 2*DIM
    ushort* rel16  = (ushort*)(stats + 2 * DIM);           // 2*N_RELC*DIM bf16
    float* outp    = (float*)d_out;
    // d_out double-duty (dead until gemm writes it):
    ushort* ent16   = (ushort*)d_out;                                    // 40MB
    uint2* csr2_in  = (uint2*)((char*)d_out + (size_t)40 * 1024 * 1024); // 8MB
    uint2* csr2_out = csr2_in + n_edge;                                  // 8MB

    hipMemsetAsync(deg_in, 0, (size_t)2 * N_ENT * sizeof(int), stream);
    hipMemsetAsync(stats, 0, (size_t)2 * DIM * sizeof(float), stream);

    prep_kernel<<<CE_B + CR_B + PB_B + DEG_B, 256, 0, stream>>>(
        ent, rel, loop_rel, w_in, w_out, w_loop, src, dst,
        ent16, rel16, BT, Abuf, deg_in, deg_out, n_edge);
    scan_part_kernel<<<2 * SCAN_NB, 256, 0, stream>>>(deg_in, deg_out, partials);
    scan_apply_kernel<<<2 * SCAN_NB, 256, 0, stream>>>(
        deg_in, deg_out, partials, off_in, off_out, cur_in, cur_out,
        inv_in, inv_out);
    fill_kernel<<<512, 256, 0, stream>>>(src, dst, etype, inv_in, inv_out,
                                         cur_in, cur_out, csr2_in, csr2_out, n_edge);
    gather_kernel<<<25000, 256, 0, stream>>>(ent16, rel16, csr2_in, csr2_out,
                                             off_in, off_out, Abuf);
    gemm_kernel<<<MPAD / BM, 512, 0, stream>>>(Abuf, BT, bias, outp, stats);
    bn_tanh_kernel<<<2048, 256, 0, stream>>>(outp, stats, gamma, beta);
}